// Round 3
// baseline (574.832 us; speedup 1.0000x reference)
//
#include <hip/hip_runtime.h>
#include <cstdint>
#include <cstddef>

#define BATCH  4
#define SEQ    2048
#define EMBED  1024
#define NHEADS 16
#define HDIM   64

typedef __attribute__((ext_vector_type(8))) short  short8;   // 8 x bf16 (4 VGPRs)
typedef __attribute__((ext_vector_type(4))) float  floatx4;  // MFMA C/D

#define MASK_NEG (-1.0e30f)   // finite "minus infinity": no inf-inf NaN paths

__device__ __forceinline__ float bf2f(ushort u) {
  union { uint32_t i; float f; } v; v.i = ((uint32_t)u) << 16; return v.f;
}
__device__ __forceinline__ ushort f2bf(float f) {
  union { float f; uint32_t i; } v; v.f = f;
  uint32_t u = v.i;
  return (ushort)((u + 0x7fffu + ((u >> 16) & 1u)) >> 16);   // RNE
}

// ---------------------------------------------------------------------------
// Dtype detection: if x is packed bf16, the LOW ushort of each 32-bit word is
// a bf16 of ~N(0,1) -> exponent field in [100,140] (or exact zero) for
// essentially all words. If x is fp32, the low ushort is random mantissa bits
// -> only ~16% land in that exponent range. 4096 words, threshold 3500.
// flag = 1 (bf16) / 0 (fp32). Deterministic on fixed input data.
// ---------------------------------------------------------------------------
__global__ __launch_bounds__(256) void detect_dtype(
    const uint32_t* __restrict__ x, int* __restrict__ flag) {
  __shared__ int sh[256];
  int tid = threadIdx.x;
  int c = 0;
#pragma unroll
  for (int i = 0; i < 16; i++) {
    uint32_t w = x[tid * 16 + i];
    uint32_t lo = w & 0xFFFFu;
    int e = (int)((lo >> 7) & 0xFF);
    if (lo == 0u || (e >= 100 && e <= 140)) c++;
  }
  sh[tid] = c;
  __syncthreads();
  if (tid == 0) {
    int s = 0;
    for (int i = 0; i < 256; i++) s += sh[i];
    *flag = (s >= 3500) ? 1 : 0;
  }
}

// ---------------------------------------------------------------------------
// Flag-driven convert to bf16 (passthrough if already bf16).
// ---------------------------------------------------------------------------
__global__ __launch_bounds__(256) void cvt_bf16(
    const void* __restrict__ in, ushort* __restrict__ out,
    const int* __restrict__ flag, int n) {
  bool isbf = (*flag != 0);
  int stride = gridDim.x * 256;
  for (int i = blockIdx.x * 256 + threadIdx.x; i < n; i += stride)
    out[i] = isbf ? ((const ushort*)in)[i] : f2bf(((const float*)in)[i]);
}

// ---------------------------------------------------------------------------
// Flag-driven transpose+convert: in [R][C] (fp32 or bf16) -> out [C][R] bf16.
// ---------------------------------------------------------------------------
__global__ __launch_bounds__(256) void transpose_cvt(
    const void* __restrict__ in, ushort* __restrict__ out,
    const int* __restrict__ flag, int R, int C) {
  bool isbf = (*flag != 0);
  __shared__ ushort tile[32][33];
  int bx = blockIdx.x * 32;           // col base in `in`
  int by = blockIdx.y * 32;           // row base in `in`
  int tx = threadIdx.x & 31, ty = threadIdx.x >> 5;   // ty in 0..7
#pragma unroll
  for (int i = 0; i < 32; i += 8) {
    size_t idx = (size_t)(by + ty + i) * C + bx + tx;
    tile[ty + i][tx] = isbf ? ((const ushort*)in)[idx] : f2bf(((const float*)in)[idx]);
  }
  __syncthreads();
#pragma unroll
  for (int i = 0; i < 32; i += 8)
    out[(size_t)(bx + ty + i) * R + by + tx] = tile[tx][ty + i];
}

// ---------------------------------------------------------------------------
// GEMM: C[M,N] = A[M,K] @ B[K,N] + bias, A row-major bf16, BT = B^T [N,K] bf16.
// 128x128 tile, BK=32, 256 thr = 4 waves (2x2 of 64x64).
// EPI==0: scatter into Q/K/V (B,H,S,D) bf16.
// EPI==1: row-major store to d_out, fp32 or bf16 per flag.
// ---------------------------------------------------------------------------
template <int EPI>
__global__ __launch_bounds__(256) void gemm128(
    const ushort* __restrict__ A, const ushort* __restrict__ BT,
    const ushort* __restrict__ bias,
    ushort* __restrict__ out0, ushort* __restrict__ out1, ushort* __restrict__ out2,
    const int* __restrict__ flag,
    int M, int N, int K) {
  __shared__ __align__(16) ushort Al[128 * 32];
  __shared__ __align__(16) ushort Bl[128 * 32];

  const int tid  = threadIdx.x;
  const int lane = tid & 63, wave = tid >> 6;
  const int quad = lane >> 4, l15 = lane & 15;
  const int wm = wave >> 1, wn = wave & 1;
  const int rowA0 = blockIdx.y * 128;
  const int colB0 = blockIdx.x * 128;

  floatx4 acc[4][4] = {};

  const int c0 = tid, c1 = tid + 256;   // 512 chunks of 8 bf16 per tile

  for (int kk = 0; kk < K; kk += 32) {
    __syncthreads();
    {
      int r = c0 >> 2, o = c0 & 3;
      *(uint4*)&Al[r * 32 + o * 8] = *(const uint4*)&A[(size_t)(rowA0 + r) * K + kk + o * 8];
      *(uint4*)&Bl[r * 32 + o * 8] = *(const uint4*)&BT[(size_t)(colB0 + r) * K + kk + o * 8];
      r = c1 >> 2; o = c1 & 3;
      *(uint4*)&Al[r * 32 + o * 8] = *(const uint4*)&A[(size_t)(rowA0 + r) * K + kk + o * 8];
      *(uint4*)&Bl[r * 32 + o * 8] = *(const uint4*)&BT[(size_t)(colB0 + r) * K + kk + o * 8];
    }
    __syncthreads();

    short8 af[4], bf[4];
#pragma unroll
    for (int mt = 0; mt < 4; mt++)
      af[mt] = *(const short8*)&Al[(wm * 64 + mt * 16 + l15) * 32 + quad * 8];
#pragma unroll
    for (int nt = 0; nt < 4; nt++)
      bf[nt] = *(const short8*)&Bl[(wn * 64 + nt * 16 + l15) * 32 + quad * 8];
#pragma unroll
    for (int mt = 0; mt < 4; mt++)
#pragma unroll
      for (int nt = 0; nt < 4; nt++)
        acc[mt][nt] = __builtin_amdgcn_mfma_f32_16x16x32_bf16(af[mt], bf[nt], acc[mt][nt], 0, 0, 0);
  }

  const bool isbf = (EPI == 1) ? (*flag != 0) : true;

#pragma unroll
  for (int mt = 0; mt < 4; mt++)
#pragma unroll
    for (int nt = 0; nt < 4; nt++)
#pragma unroll
      for (int r = 0; r < 4; r++) {
        int row = rowA0 + wm * 64 + mt * 16 + quad * 4 + r;
        int col = colB0 + wn * 64 + nt * 16 + l15;
        float v = acc[mt][nt][r] + bf2f(bias[col]);
        if (EPI == 0) {
          int three = col >> 10, rem = col & 1023, h = rem >> 6, d = rem & 63;
          int b = row >> 11, s = row & 2047;
          ushort* dst = (three == 0) ? out0 : (three == 1) ? out1 : out2;
          dst[((size_t)(b * NHEADS + h) * SEQ + s) * HDIM + d] = f2bf(v);
        } else {
          if (isbf) out0[(size_t)row * N + col] = f2bf(v);
          else      ((float*)out0)[(size_t)row * N + col] = v;
        }
      }
}

// ---------------------------------------------------------------------------
// Flash attention, causal + ALiBi. Q/K/V (B,H,S,D) bf16. Out (B,S,H,D) bf16.
// Block: 64 q-rows, 4 waves x 16 rows. K-tiles of 64 keys.
// ---------------------------------------------------------------------------
__global__ __launch_bounds__(256) void attn_kernel(
    const ushort* __restrict__ Q, const ushort* __restrict__ K,
    const ushort* __restrict__ V, ushort* __restrict__ Oout) {
  __shared__ __align__(16) ushort Kl[64 * 72];      // [key][d], pad->72 elems
  __shared__ __align__(16) ushort Vt[64 * 72];      // [d][key], pad->72 elems
  __shared__ __align__(16) ushort Pl[4][16 * 64];   // per-wave P round-trip

  const int tid  = threadIdx.x;
  const int lane = tid & 63, wave = tid >> 6;
  const int quad = lane >> 4, l15 = lane & 15;
  const int qt = blockIdx.x, h = blockIdx.y, b = blockIdx.z;
  const int bh = b * NHEADS + h;
  const ushort* Qp = Q + (size_t)bh * SEQ * HDIM;
  const ushort* Kp = K + (size_t)bh * SEQ * HDIM;
  const ushort* Vp = V + (size_t)bh * SEQ * HDIM;
  const int qbase = qt * 64;

  // Q fragments (A-operand): rows qbase + wave*16 + l15
  const int qrowA = qbase + wave * 16 + l15;
  short8 qf[2];
  qf[0] = *(const short8*)&Qp[(size_t)qrowA * HDIM + quad * 8];
  qf[1] = *(const short8*)&Qp[(size_t)qrowA * HDIM + 32 + quad * 8];

  const float slope = exp2f(-0.5f * (float)(h + 1));

  float m_i[4], l_i[4];
  floatx4 o_acc[4] = {};
  int qrow_c[4];
#pragma unroll
  for (int r = 0; r < 4; r++) {
    m_i[r] = MASK_NEG; l_i[r] = 0.f;
    qrow_c[r] = qbase + wave * 16 + quad * 4 + r;
  }

  for (int kt = 0; kt <= qt; kt++) {
    const int kb = kt * 64;
    __syncthreads();
    // stage K (row-major, pad 72) and V (transposed [d][key], pad 72)
    for (int c = tid; c < 512; c += 256) {
      int key = c >> 3, o = c & 7;
      uint4 kv = *(const uint4*)&Kp[(size_t)(kb + key) * HDIM + o * 8];
      *(uint4*)&Kl[key * 72 + o * 8] = kv;
      uint4 vv = *(const uint4*)&Vp[(size_t)(kb + key) * HDIM + o * 8];
      const ushort* e = (const ushort*)&vv;
#pragma unroll
      for (int i = 0; i < 8; i++) Vt[(o * 8 + i) * 72 + key] = e[i];
    }
    __syncthreads();

    // scores: S = Q . K^T   (16 q-rows x 64 keys per wave)
    floatx4 sc[4] = {};
#pragma unroll
    for (int ct = 0; ct < 4; ct++) {
      short8 kf0 = *(const short8*)&Kl[(ct * 16 + l15) * 72 + quad * 8];
      short8 kf1 = *(const short8*)&Kl[(ct * 16 + l15) * 72 + 32 + quad * 8];
      sc[ct] = __builtin_amdgcn_mfma_f32_16x16x32_bf16(qf[0], kf0, sc[ct], 0, 0, 0);
      sc[ct] = __builtin_amdgcn_mfma_f32_16x16x32_bf16(qf[1], kf1, sc[ct], 0, 0, 0);
    }

    // scale + alibi + causal mask; online softmax (all finite arithmetic)
    float sval[4][4];
    float rowmax[4] = {MASK_NEG, MASK_NEG, MASK_NEG, MASK_NEG};
#pragma unroll
    for (int ct = 0; ct < 4; ct++)
#pragma unroll
      for (int r = 0; r < 4; r++) {
        int key = kb + ct * 16 + l15;
        float v = sc[ct][r] * 0.125f + slope * (float)(key - qrow_c[r]);
        if (key > qrow_c[r]) v = MASK_NEG;
        sval[ct][r] = v;
        rowmax[r] = fmaxf(rowmax[r], v);
      }
#pragma unroll
    for (int r = 0; r < 4; r++)
      for (int off = 1; off < 16; off <<= 1)
        rowmax[r] = fmaxf(rowmax[r], __shfl_xor(rowmax[r], off, 64));

    float alpha[4], rowsum[4];
#pragma unroll
    for (int r = 0; r < 4; r++) {
      float mn = fmaxf(m_i[r], rowmax[r]);
      alpha[r] = __expf(m_i[r] - mn);
      m_i[r] = mn;
      rowsum[r] = 0.f;
    }
#pragma unroll
    for (int ct = 0; ct < 4; ct++)
#pragma unroll
      for (int r = 0; r < 4; r++) {
        float p = __expf(sval[ct][r] - m_i[r]);
        rowsum[r] += p;
        Pl[wave][(quad * 4 + r) * 64 + ct * 16 + l15] = f2bf(p);
      }
#pragma unroll
    for (int r = 0; r < 4; r++) {
      for (int off = 1; off < 16; off <<= 1)
        rowsum[r] += __shfl_xor(rowsum[r], off, 64);
      l_i[r] = l_i[r] * alpha[r] + rowsum[r];
    }
#pragma unroll
    for (int ct = 0; ct < 4; ct++)
#pragma unroll
      for (int r = 0; r < 4; r++) o_acc[ct][r] *= alpha[r];

    __syncthreads();   // P visible (also within-wave LDS write->read ordering)

    // O += P . V
#pragma unroll
    for (int ks = 0; ks < 2; ks++) {
      short8 pf = *(const short8*)&Pl[wave][l15 * 64 + ks * 32 + quad * 8];
#pragma unroll
      for (int ct = 0; ct < 4; ct++) {
        short8 vf = *(const short8*)&Vt[(ct * 16 + l15) * 72 + ks * 32 + quad * 8];
        o_acc[ct] = __builtin_amdgcn_mfma_f32_16x16x32_bf16(pf, vf, o_acc[ct], 0, 0, 0);
      }
    }
  }

  // write (B,S,H,D) == (B,S,E) rows for the output GEMM
#pragma unroll
  for (int ct = 0; ct < 4; ct++)
#pragma unroll
    for (int r = 0; r < 4; r++) {
      int q = qrow_c[r];
      float inv_l = 1.0f / fmaxf(l_i[r], 1e-20f);
      float v = o_acc[ct][r] * inv_l;
      Oout[(size_t)(b * SEQ + q) * EMBED + h * HDIM + ct * 16 + l15] = f2bf(v);
    }
}

// ---------------------------------------------------------------------------
// ws layout (bytes), all bf16 buffers:
//   flag @ 0          (1024 reserved)
//   xb   @ 1024       16777216   x as bf16 (B,S,E)
//   WTq  @ 16778240    6291456   W_qkv^T bf16
//   WTo  @ 23069696    2097152   W_out^T bf16
//   bqb  @ 25166848       6144   b_qkv bf16
//   bob  @ 25172992       2048   b_out bf16
//   Kw   @ 25175040   16777216
//   Vw   @ 41952256   16777216
//   Aw   @ 58729472   16777216   -> end 75506688 (~72 MiB)
//   Qw   @ 75506688 if ws fits, else Q lives in d_out (>=16 MiB both dtypes;
//                     fully overwritten by the final GEMM afterwards)
// ---------------------------------------------------------------------------
extern "C" void kernel_launch(void* const* d_in, const int* in_sizes, int n_in,
                              void* d_out, int out_size, void* d_ws, size_t ws_size,
                              hipStream_t stream) {
  const void* x     = d_in[0];
  // d_in[1] = mask (causal tril) — computed analytically, not read
  const void* W_qkv = d_in[2];
  const void* b_qkv = d_in[3];
  const void* W_out = d_in[4];
  const void* b_out = d_in[5];

  char* ws = (char*)d_ws;
  int*    flag = (int*)(ws + 0);
  ushort* xb   = (ushort*)(ws + 1024);
  ushort* WTq  = (ushort*)(ws + 16778240);
  ushort* WTo  = (ushort*)(ws + 23069696);
  ushort* bqb  = (ushort*)(ws + 25166848);
  ushort* bob  = (ushort*)(ws + 25172992);
  ushort* Kw   = (ushort*)(ws + 25175040);
  ushort* Vw   = (ushort*)(ws + 41952256);
  ushort* Aw   = (ushort*)(ws + 58729472);
  ushort* Qw   = (ws_size >= (size_t)75506688 + 16777216)
                   ? (ushort*)(ws + 75506688)
                   : (ushort*)d_out;   // d_out as scratch: dead until final GEMM

  detect_dtype<<<1, 256, 0, stream>>>((const uint32_t*)x, flag);

  cvt_bf16<<<4096, 256, 0, stream>>>(x, xb, flag, BATCH * SEQ * EMBED);
  cvt_bf16<<<16, 256, 0, stream>>>(b_qkv, bqb, flag, 3 * EMBED);
  cvt_bf16<<<8, 256, 0, stream>>>(b_out, bob, flag, EMBED);

  transpose_cvt<<<dim3(3072 / 32, 1024 / 32), 256, 0, stream>>>(W_qkv, WTq, flag, 1024, 3072);
  transpose_cvt<<<dim3(1024 / 32, 1024 / 32), 256, 0, stream>>>(W_out, WTo, flag, 1024, 1024);

  gemm128<0><<<dim3(3072 / 128, 8192 / 128), 256, 0, stream>>>(
      xb, WTq, bqb, Qw, Kw, Vw, flag, BATCH * SEQ, 3 * EMBED, EMBED);

  attn_kernel<<<dim3(SEQ / 64, NHEADS, BATCH), 256, 0, stream>>>(Qw, Kw, Vw, Aw);

  gemm128<1><<<dim3(1024 / 128, 8192 / 128), 256, 0, stream>>>(
      Aw, WTo, bob, (ushort*)d_out, nullptr, nullptr, flag, BATCH * SEQ, EMBED, EMBED);
}

// Round 4
// 522.931 us; speedup vs baseline: 1.0993x; 1.0993x over previous
//
#include <hip/hip_runtime.h>
#include <cstdint>
#include <cstddef>

#define BATCH  4
#define SEQ    2048
#define EMBED  1024
#define NHEADS 16
#define HDIM   64

typedef __attribute__((ext_vector_type(8))) short  short8;   // 8 x bf16 (4 VGPRs)
typedef __attribute__((ext_vector_type(4))) float  floatx4;  // MFMA C/D

#define MASK_NEG (-1.0e30f)   // finite "minus infinity": no inf-inf NaN paths

__device__ __forceinline__ float bf2f(ushort u) {
  union { uint32_t i; float f; } v; v.i = ((uint32_t)u) << 16; return v.f;
}
__device__ __forceinline__ ushort f2bf(float f) {
  union { float f; uint32_t i; } v; v.f = f;
  uint32_t u = v.i;
  return (ushort)((u + 0x7fffu + ((u >> 16) & 1u)) >> 16);   // RNE
}

// ---------------------------------------------------------------------------
// Dtype detection (flag=1 bf16-packed, 0 fp32). Verified working in round 3.
// ---------------------------------------------------------------------------
__global__ __launch_bounds__(256) void detect_dtype(
    const uint32_t* __restrict__ x, int* __restrict__ flag) {
  __shared__ int sh[256];
  int tid = threadIdx.x;
  int c = 0;
#pragma unroll
  for (int i = 0; i < 16; i++) {
    uint32_t w = x[tid * 16 + i];
    uint32_t lo = w & 0xFFFFu;
    int e = (int)((lo >> 7) & 0xFF);
    if (lo == 0u || (e >= 100 && e <= 140)) c++;
  }
  sh[tid] = c;
  __syncthreads();
  if (tid == 0) {
    int s = 0;
    for (int i = 0; i < 256; i++) s += sh[i];
    *flag = (s >= 3500) ? 1 : 0;
  }
}

__global__ __launch_bounds__(256) void cvt_bf16(
    const void* __restrict__ in, ushort* __restrict__ out,
    const int* __restrict__ flag, int n) {
  bool isbf = (*flag != 0);
  int stride = gridDim.x * 256;
  for (int i = blockIdx.x * 256 + threadIdx.x; i < n; i += stride)
    out[i] = isbf ? ((const ushort*)in)[i] : f2bf(((const float*)in)[i]);
}

__global__ __launch_bounds__(256) void transpose_cvt(
    const void* __restrict__ in, ushort* __restrict__ out,
    const int* __restrict__ flag, int R, int C) {
  bool isbf = (*flag != 0);
  __shared__ ushort tile[32][33];
  int bx = blockIdx.x * 32;
  int by = blockIdx.y * 32;
  int tx = threadIdx.x & 31, ty = threadIdx.x >> 5;
#pragma unroll
  for (int i = 0; i < 32; i += 8) {
    size_t idx = (size_t)(by + ty + i) * C + bx + tx;
    tile[ty + i][tx] = isbf ? ((const ushort*)in)[idx] : f2bf(((const float*)in)[idx]);
  }
  __syncthreads();
#pragma unroll
  for (int i = 0; i < 32; i += 8)
    out[(size_t)(bx + ty + i) * R + by + tx] = tile[tx][ty + i];
}

// ---------------------------------------------------------------------------
// Batched transpose: V (BH, S, D) bf16 -> VT (BH, D, S) bf16.
// ---------------------------------------------------------------------------
__global__ __launch_bounds__(256) void transpose_v(
    const ushort* __restrict__ in, ushort* __restrict__ out) {
  __shared__ ushort tile[32][33];
  int bh = blockIdx.z;
  int s0 = blockIdx.x * 32;
  int d0 = blockIdx.y * 32;
  int tx = threadIdx.x & 31, ty = threadIdx.x >> 5;
  const ushort* ip = in + (size_t)bh * SEQ * HDIM;
  ushort* op = out + (size_t)bh * SEQ * HDIM;
#pragma unroll
  for (int i = 0; i < 32; i += 8)
    tile[ty + i][tx] = ip[(size_t)(s0 + ty + i) * HDIM + d0 + tx];
  __syncthreads();
#pragma unroll
  for (int i = 0; i < 32; i += 8)
    op[(size_t)(d0 + ty + i) * SEQ + s0 + tx] = tile[tx][ty + i];
}

// ---------------------------------------------------------------------------
// GEMM (unchanged from passing round 3).
// ---------------------------------------------------------------------------
template <int EPI>
__global__ __launch_bounds__(256) void gemm128(
    const ushort* __restrict__ A, const ushort* __restrict__ BT,
    const ushort* __restrict__ bias,
    ushort* __restrict__ out0, ushort* __restrict__ out1, ushort* __restrict__ out2,
    const int* __restrict__ flag,
    int M, int N, int K) {
  __shared__ __align__(16) ushort Al[128 * 32];
  __shared__ __align__(16) ushort Bl[128 * 32];

  const int tid  = threadIdx.x;
  const int lane = tid & 63, wave = tid >> 6;
  const int quad = lane >> 4, l15 = lane & 15;
  const int wm = wave >> 1, wn = wave & 1;
  const int rowA0 = blockIdx.y * 128;
  const int colB0 = blockIdx.x * 128;

  floatx4 acc[4][4] = {};

  const int c0 = tid, c1 = tid + 256;

  for (int kk = 0; kk < K; kk += 32) {
    __syncthreads();
    {
      int r = c0 >> 2, o = c0 & 3;
      *(uint4*)&Al[r * 32 + o * 8] = *(const uint4*)&A[(size_t)(rowA0 + r) * K + kk + o * 8];
      *(uint4*)&Bl[r * 32 + o * 8] = *(const uint4*)&BT[(size_t)(colB0 + r) * K + kk + o * 8];
      r = c1 >> 2; o = c1 & 3;
      *(uint4*)&Al[r * 32 + o * 8] = *(const uint4*)&A[(size_t)(rowA0 + r) * K + kk + o * 8];
      *(uint4*)&Bl[r * 32 + o * 8] = *(const uint4*)&BT[(size_t)(colB0 + r) * K + kk + o * 8];
    }
    __syncthreads();

    short8 af[4], bf[4];
#pragma unroll
    for (int mt = 0; mt < 4; mt++)
      af[mt] = *(const short8*)&Al[(wm * 64 + mt * 16 + l15) * 32 + quad * 8];
#pragma unroll
    for (int nt = 0; nt < 4; nt++)
      bf[nt] = *(const short8*)&Bl[(wn * 64 + nt * 16 + l15) * 32 + quad * 8];
#pragma unroll
    for (int mt = 0; mt < 4; mt++)
#pragma unroll
      for (int nt = 0; nt < 4; nt++)
        acc[mt][nt] = __builtin_amdgcn_mfma_f32_16x16x32_bf16(af[mt], bf[nt], acc[mt][nt], 0, 0, 0);
  }

  const bool isbf = (EPI == 1) ? (*flag != 0) : true;

#pragma unroll
  for (int mt = 0; mt < 4; mt++)
#pragma unroll
    for (int nt = 0; nt < 4; nt++)
#pragma unroll
      for (int r = 0; r < 4; r++) {
        int row = rowA0 + wm * 64 + mt * 16 + quad * 4 + r;
        int col = colB0 + wn * 64 + nt * 16 + l15;
        float v = acc[mt][nt][r] + bf2f(bias[col]);
        if (EPI == 0) {
          int three = col >> 10, rem = col & 1023, h = rem >> 6, d = rem & 63;
          int b = row >> 11, s = row & 2047;
          ushort* dst = (three == 0) ? out0 : (three == 1) ? out1 : out2;
          dst[((size_t)(b * NHEADS + h) * SEQ + s) * HDIM + d] = f2bf(v);
        } else {
          if (isbf) out0[(size_t)row * N + col] = f2bf(v);
          else      ((float*)out0)[(size_t)row * N + col] = v;
        }
      }
}

// ---------------------------------------------------------------------------
// Flash attention v2. Q,K (B,H,S,D); VT (B,H,D,S); out (B,S,H,D), all bf16.
// 128 q-rows/block, 4 waves x 32 rows (2 m-frags). K-tiles of 64 keys.
// Kl/Vt rows padded to 72 elems (uniform b128 bank phases); Pl rows 68 elems
// (34 words -> store bank = 8q+2r+8ct+l15/2: full 32-bank spread).
// ---------------------------------------------------------------------------
__global__ __launch_bounds__(256, 3) void attn_kernel(
    const ushort* __restrict__ Q, const ushort* __restrict__ K,
    const ushort* __restrict__ VT, ushort* __restrict__ Oout) {
  __shared__ __align__(16) ushort Kl[64 * 72];       // [key][d]
  __shared__ __align__(16) ushort Vt[64 * 72];       // [d][key]
  __shared__ __align__(16) ushort Pl[4][32 * 68];    // per-wave [qrow][key]

  const int tid  = threadIdx.x;
  const int lane = tid & 63, wave = tid >> 6;
  const int quad = lane >> 4, l15 = lane & 15;
  const int qt = (gridDim.x - 1) - blockIdx.x;       // big blocks dispatch first
  const int h = blockIdx.y, b = blockIdx.z;
  const int bh = b * NHEADS + h;
  const ushort* Qp  = Q  + (size_t)bh * SEQ * HDIM;
  const ushort* Kp  = K  + (size_t)bh * SEQ * HDIM;
  const ushort* VTp = VT + (size_t)bh * SEQ * HDIM;  // [d][s]
  const int qbase = qt * 128;
  const int wq0 = qbase + wave * 32;                 // wave's first q-row

  // Q fragments: rows wq0 + mf*16 + l15
  short8 qf[2][2];
#pragma unroll
  for (int mf = 0; mf < 2; mf++) {
    const ushort* qr = &Qp[(size_t)(wq0 + mf * 16 + l15) * HDIM];
    qf[mf][0] = *(const short8*)&qr[quad * 8];
    qf[mf][1] = *(const short8*)&qr[32 + quad * 8];
  }

  const float slope = exp2f(-0.5f * (float)(h + 1));

  float m_i[2][4], l_i[2][4];
  floatx4 o_acc[2][4] = {};
  int qrow_c[2][4];
#pragma unroll
  for (int mf = 0; mf < 2; mf++)
#pragma unroll
    for (int r = 0; r < 4; r++) {
      m_i[mf][r] = MASK_NEG; l_i[mf][r] = 0.f;
      qrow_c[mf][r] = wq0 + mf * 16 + quad * 4 + r;
    }
  const int wqmax = wq0 + 31;

  const int ntiles = 2 * qt + 2;
  for (int kt = 0; kt < ntiles; kt++) {
    const int kb = kt * 64;
    __syncthreads();
    // stage K [key][d] and V^T [d][key]; both b128, uniform bank phases
    for (int c = tid; c < 512; c += 256) {
      int r = c >> 3, o = c & 7;
      *(uint4*)&Kl[r * 72 + o * 8] = *(const uint4*)&Kp[(size_t)(kb + r) * HDIM + o * 8];
      *(uint4*)&Vt[r * 72 + o * 8] = *(const uint4*)&VTp[(size_t)r * SEQ + kb + o * 8];
    }
    __syncthreads();

    if (kb > wqmax) continue;                        // fully masked for this wave
    const bool needs_mask = (kb + 63 > wq0);

#pragma unroll
    for (int mf = 0; mf < 2; mf++) {
      // scores: 16 q-rows x 64 keys
      floatx4 sc[4];
#pragma unroll
      for (int ct = 0; ct < 4; ct++) {
        short8 kf0 = *(const short8*)&Kl[(ct * 16 + l15) * 72 + quad * 8];
        short8 kf1 = *(const short8*)&Kl[(ct * 16 + l15) * 72 + 32 + quad * 8];
        floatx4 z = {};
        z = __builtin_amdgcn_mfma_f32_16x16x32_bf16(qf[mf][0], kf0, z, 0, 0, 0);
        sc[ct] = __builtin_amdgcn_mfma_f32_16x16x32_bf16(qf[mf][1], kf1, z, 0, 0, 0);
      }

      float rowmax[4] = {MASK_NEG, MASK_NEG, MASK_NEG, MASK_NEG};
#pragma unroll
      for (int ct = 0; ct < 4; ct++)
#pragma unroll
        for (int r = 0; r < 4; r++) {
          int key = kb + ct * 16 + l15;
          float v = sc[ct][r] * 0.125f + slope * (float)(key - qrow_c[mf][r]);
          if (needs_mask && key > qrow_c[mf][r]) v = MASK_NEG;
          sc[ct][r] = v;
          rowmax[r] = fmaxf(rowmax[r], v);
        }
#pragma unroll
      for (int r = 0; r < 4; r++)
        for (int off = 1; off < 16; off <<= 1)
          rowmax[r] = fmaxf(rowmax[r], __shfl_xor(rowmax[r], off, 64));

      float alpha[4], rowsum[4];
#pragma unroll
      for (int r = 0; r < 4; r++) {
        float mn = fmaxf(m_i[mf][r], rowmax[r]);
        alpha[r] = __expf(m_i[mf][r] - mn);
        m_i[mf][r] = mn;
        rowsum[r] = 0.f;
      }
#pragma unroll
      for (int ct = 0; ct < 4; ct++)
#pragma unroll
        for (int r = 0; r < 4; r++) {
          float p = __expf(sc[ct][r] - m_i[mf][r]);
          rowsum[r] += p;
          Pl[wave][(mf * 16 + quad * 4 + r) * 68 + ct * 16 + l15] = f2bf(p);
        }
#pragma unroll
      for (int r = 0; r < 4; r++) {
        for (int off = 1; off < 16; off <<= 1)
          rowsum[r] += __shfl_xor(rowsum[r], off, 64);
        l_i[mf][r] = l_i[mf][r] * alpha[r] + rowsum[r];
      }
#pragma unroll
      for (int ct = 0; ct < 4; ct++)
#pragma unroll
        for (int r = 0; r < 4; r++) o_acc[mf][ct][r] *= alpha[r];
    }

    // O += P . V   (Pl is per-wave: no barrier needed, lgkmcnt orders it)
#pragma unroll
    for (int ks = 0; ks < 2; ks++) {
      short8 vf[4];
#pragma unroll
      for (int ct = 0; ct < 4; ct++)
        vf[ct] = *(const short8*)&Vt[(ct * 16 + l15) * 72 + ks * 32 + quad * 8];
#pragma unroll
      for (int mf = 0; mf < 2; mf++) {
        union { short8 v; uint2 u[2]; } pu;
        const ushort* pb = &Pl[wave][(mf * 16 + l15) * 68 + ks * 32 + quad * 8];
        pu.u[0] = *(const uint2*)(pb);
        pu.u[1] = *(const uint2*)(pb + 4);
#pragma unroll
        for (int ct = 0; ct < 4; ct++)
          o_acc[mf][ct] = __builtin_amdgcn_mfma_f32_16x16x32_bf16(pu.v, vf[ct], o_acc[mf][ct], 0, 0, 0);
      }
    }
  }

  // write (B,S,H,D) == (B,S,E)
#pragma unroll
  for (int mf = 0; mf < 2; mf++)
#pragma unroll
    for (int ct = 0; ct < 4; ct++)
#pragma unroll
      for (int r = 0; r < 4; r++) {
        int q = qrow_c[mf][r];
        float inv_l = 1.0f / fmaxf(l_i[mf][r], 1e-20f);
        float v = o_acc[mf][ct][r] * inv_l;
        Oout[(size_t)(b * SEQ + q) * EMBED + h * HDIM + ct * 16 + l15] = f2bf(v);
      }
}

// ---------------------------------------------------------------------------
// ws layout (bytes):
//   flag @ 0          (1024)
//   xb   @ 1024       16777216
//   WTq  @ 16778240    6291456
//   WTo  @ 23069696    2097152
//   bqb  @ 25166848       6144
//   bob  @ 25172992       2048
//   Kw   @ 25175040   16777216
//   Vw   @ 41952256   16777216   (dead after transpose_v -> reused as Aw)
//   VT   @ 58729472   16777216   -> end 75506688 (same envelope as round 3)
//   Qw   @ 75506688 if ws fits, else Q lives in d_out.
// ---------------------------------------------------------------------------
extern "C" void kernel_launch(void* const* d_in, const int* in_sizes, int n_in,
                              void* d_out, int out_size, void* d_ws, size_t ws_size,
                              hipStream_t stream) {
  const void* x     = d_in[0];
  const void* W_qkv = d_in[2];
  const void* b_qkv = d_in[3];
  const void* W_out = d_in[4];
  const void* b_out = d_in[5];

  char* ws = (char*)d_ws;
  int*    flag = (int*)(ws + 0);
  ushort* xb   = (ushort*)(ws + 1024);
  ushort* WTq  = (ushort*)(ws + 16778240);
  ushort* WTo  = (ushort*)(ws + 23069696);
  ushort* bqb  = (ushort*)(ws + 25166848);
  ushort* bob  = (ushort*)(ws + 25172992);
  ushort* Kw   = (ushort*)(ws + 25175040);
  ushort* Vw   = (ushort*)(ws + 41952256);
  ushort* VTw  = (ushort*)(ws + 58729472);
  ushort* Aw   = Vw;   // Vw dead after transpose_v
  ushort* Qw   = (ws_size >= (size_t)75506688 + 16777216)
                   ? (ushort*)(ws + 75506688)
                   : (ushort*)d_out;   // d_out as scratch: dead until final GEMM

  detect_dtype<<<1, 256, 0, stream>>>((const uint32_t*)x, flag);

  cvt_bf16<<<4096, 256, 0, stream>>>(x, xb, flag, BATCH * SEQ * EMBED);
  cvt_bf16<<<16, 256, 0, stream>>>(b_qkv, bqb, flag, 3 * EMBED);
  cvt_bf16<<<8, 256, 0, stream>>>(b_out, bob, flag, EMBED);

  transpose_cvt<<<dim3(3072 / 32, 1024 / 32), 256, 0, stream>>>(W_qkv, WTq, flag, 1024, 3072);
  transpose_cvt<<<dim3(1024 / 32, 1024 / 32), 256, 0, stream>>>(W_out, WTo, flag, 1024, 1024);

  gemm128<0><<<dim3(3072 / 128, 8192 / 128), 256, 0, stream>>>(
      xb, WTq, bqb, Qw, Kw, Vw, flag, BATCH * SEQ, 3 * EMBED, EMBED);

  transpose_v<<<dim3(SEQ / 32, HDIM / 32, BATCH * NHEADS), 256, 0, stream>>>(Vw, VTw);

  attn_kernel<<<dim3(SEQ / 128, NHEADS, BATCH), 256, 0, stream>>>(Qw, Kw, VTw, Aw);

  gemm128<1><<<dim3(1024 / 128, 8192 / 128), 256, 0, stream>>>(
      Aw, WTo, bob, (ushort*)d_out, nullptr, nullptr, flag, BATCH * SEQ, EMBED, EMBED);
}

// Round 5
// 395.760 us; speedup vs baseline: 1.4525x; 1.3213x over previous
//
#include <hip/hip_runtime.h>
#include <cstdint>
#include <cstddef>

#define BATCH  4
#define SEQ    2048
#define EMBED  1024
#define NHEADS 16
#define HDIM   64

typedef __attribute__((ext_vector_type(8))) short  short8;   // 8 x bf16 (4 VGPRs)
typedef __attribute__((ext_vector_type(4))) float  floatx4;  // MFMA C/D

#define MASK_NEG (-1.0e30f)   // finite "minus infinity": no inf-inf NaN paths
#define LOG2E    1.44269504f

__device__ __forceinline__ float bf2f(ushort u) {
  union { uint32_t i; float f; } v; v.i = ((uint32_t)u) << 16; return v.f;
}
__device__ __forceinline__ ushort f2bf(float f) {
  union { float f; uint32_t i; } v; v.f = f;
  uint32_t u = v.i;
  return (ushort)((u + 0x7fffu + ((u >> 16) & 1u)) >> 16);   // RNE
}

// ---------------------------------------------------------------------------
// Dtype detection (flag=1 bf16-packed, 0 fp32). Verified working in round 3.
// ---------------------------------------------------------------------------
__global__ __launch_bounds__(256) void detect_dtype(
    const uint32_t* __restrict__ x, int* __restrict__ flag) {
  __shared__ int sh[256];
  int tid = threadIdx.x;
  int c = 0;
#pragma unroll
  for (int i = 0; i < 16; i++) {
    uint32_t w = x[tid * 16 + i];
    uint32_t lo = w & 0xFFFFu;
    int e = (int)((lo >> 7) & 0xFF);
    if (lo == 0u || (e >= 100 && e <= 140)) c++;
  }
  sh[tid] = c;
  __syncthreads();
  if (tid == 0) {
    int s = 0;
    for (int i = 0; i < 256; i++) s += sh[i];
    *flag = (s >= 3500) ? 1 : 0;
  }
}

__global__ __launch_bounds__(256) void cvt_bf16(
    const void* __restrict__ in, ushort* __restrict__ out,
    const int* __restrict__ flag, int n) {
  bool isbf = (*flag != 0);
  int stride = gridDim.x * 256;
  for (int i = blockIdx.x * 256 + threadIdx.x; i < n; i += stride)
    out[i] = isbf ? ((const ushort*)in)[i] : f2bf(((const float*)in)[i]);
}

__global__ __launch_bounds__(256) void transpose_cvt(
    const void* __restrict__ in, ushort* __restrict__ out,
    const int* __restrict__ flag, int R, int C) {
  bool isbf = (*flag != 0);
  __shared__ ushort tile[32][33];
  int bx = blockIdx.x * 32;
  int by = blockIdx.y * 32;
  int tx = threadIdx.x & 31, ty = threadIdx.x >> 5;
#pragma unroll
  for (int i = 0; i < 32; i += 8) {
    size_t idx = (size_t)(by + ty + i) * C + bx + tx;
    tile[ty + i][tx] = isbf ? ((const ushort*)in)[idx] : f2bf(((const float*)in)[idx]);
  }
  __syncthreads();
#pragma unroll
  for (int i = 0; i < 32; i += 8)
    out[(size_t)(bx + ty + i) * R + by + tx] = tile[tx][ty + i];
}

// ---------------------------------------------------------------------------
// Batched transpose: V (BH, S, D) bf16 -> VT (BH, D, S) bf16.
// ---------------------------------------------------------------------------
__global__ __launch_bounds__(256) void transpose_v(
    const ushort* __restrict__ in, ushort* __restrict__ out) {
  __shared__ ushort tile[32][33];
  int bh = blockIdx.z;
  int s0 = blockIdx.x * 32;
  int d0 = blockIdx.y * 32;
  int tx = threadIdx.x & 31, ty = threadIdx.x >> 5;
  const ushort* ip = in + (size_t)bh * SEQ * HDIM;
  ushort* op = out + (size_t)bh * SEQ * HDIM;
#pragma unroll
  for (int i = 0; i < 32; i += 8)
    tile[ty + i][tx] = ip[(size_t)(s0 + ty + i) * HDIM + d0 + tx];
  __syncthreads();
#pragma unroll
  for (int i = 0; i < 32; i += 8)
    op[(size_t)(d0 + ty + i) * SEQ + s0 + tx] = tile[tx][ty + i];
}

// ---------------------------------------------------------------------------
// GEMM (unchanged from passing rounds 3/4).
// ---------------------------------------------------------------------------
template <int EPI>
__global__ __launch_bounds__(256) void gemm128(
    const ushort* __restrict__ A, const ushort* __restrict__ BT,
    const ushort* __restrict__ bias,
    ushort* __restrict__ out0, ushort* __restrict__ out1, ushort* __restrict__ out2,
    const int* __restrict__ flag,
    int M, int N, int K) {
  __shared__ __align__(16) ushort Al[128 * 32];
  __shared__ __align__(16) ushort Bl[128 * 32];

  const int tid  = threadIdx.x;
  const int lane = tid & 63, wave = tid >> 6;
  const int quad = lane >> 4, l15 = lane & 15;
  const int wm = wave >> 1, wn = wave & 1;
  const int rowA0 = blockIdx.y * 128;
  const int colB0 = blockIdx.x * 128;

  floatx4 acc[4][4] = {};

  const int c0 = tid, c1 = tid + 256;

  for (int kk = 0; kk < K; kk += 32) {
    __syncthreads();
    {
      int r = c0 >> 2, o = c0 & 3;
      *(uint4*)&Al[r * 32 + o * 8] = *(const uint4*)&A[(size_t)(rowA0 + r) * K + kk + o * 8];
      *(uint4*)&Bl[r * 32 + o * 8] = *(const uint4*)&BT[(size_t)(colB0 + r) * K + kk + o * 8];
      r = c1 >> 2; o = c1 & 3;
      *(uint4*)&Al[r * 32 + o * 8] = *(const uint4*)&A[(size_t)(rowA0 + r) * K + kk + o * 8];
      *(uint4*)&Bl[r * 32 + o * 8] = *(const uint4*)&BT[(size_t)(colB0 + r) * K + kk + o * 8];
    }
    __syncthreads();

    short8 af[4], bf[4];
#pragma unroll
    for (int mt = 0; mt < 4; mt++)
      af[mt] = *(const short8*)&Al[(wm * 64 + mt * 16 + l15) * 32 + quad * 8];
#pragma unroll
    for (int nt = 0; nt < 4; nt++)
      bf[nt] = *(const short8*)&Bl[(wn * 64 + nt * 16 + l15) * 32 + quad * 8];
#pragma unroll
    for (int mt = 0; mt < 4; mt++)
#pragma unroll
      for (int nt = 0; nt < 4; nt++)
        acc[mt][nt] = __builtin_amdgcn_mfma_f32_16x16x32_bf16(af[mt], bf[nt], acc[mt][nt], 0, 0, 0);
  }

  const bool isbf = (EPI == 1) ? (*flag != 0) : true;

#pragma unroll
  for (int mt = 0; mt < 4; mt++)
#pragma unroll
    for (int nt = 0; nt < 4; nt++)
#pragma unroll
      for (int r = 0; r < 4; r++) {
        int row = rowA0 + wm * 64 + mt * 16 + quad * 4 + r;
        int col = colB0 + wn * 64 + nt * 16 + l15;
        float v = acc[mt][nt][r] + bf2f(bias[col]);
        if (EPI == 0) {
          int three = col >> 10, rem = col & 1023, h = rem >> 6, d = rem & 63;
          int b = row >> 11, s = row & 2047;
          ushort* dst = (three == 0) ? out0 : (three == 1) ? out1 : out2;
          dst[((size_t)(b * NHEADS + h) * SEQ + s) * HDIM + d] = f2bf(v);
        } else {
          if (isbf) out0[(size_t)row * N + col] = f2bf(v);
          else      ((float*)out0)[(size_t)row * N + col] = v;
        }
      }
}

// ---------------------------------------------------------------------------
// Flash attention v3. Q,K (B,H,S,D); VT (B,H,D,S); out (B,S,H,D), all bf16.
//  - Diagonal pairing: block pair i handles q-tiles {i, 15-i} sequentially ->
//    every block does exactly 34 k-tile iterations (perfect balance; grid 512
//    = 2 blocks/CU, occupancy flat for the whole dispatch).
//  - Double-buffered K/V staging: global->reg prefetch of tile kt+1 issued
//    before compute of tile kt; regs->LDS(other buffer) after compute; ONE
//    barrier per iteration. Global-load latency off the critical path.
//  - exp2-domain softmax (native v_exp_f32), float rel/mask precompute.
// ---------------------------------------------------------------------------
__global__ __launch_bounds__(256, 2) void attn_kernel(
    const ushort* __restrict__ Q, const ushort* __restrict__ K,
    const ushort* __restrict__ VT, ushort* __restrict__ Oout) {
  __shared__ __align__(16) ushort Kl[2][64 * 72];    // [key][d]
  __shared__ __align__(16) ushort Vt[2][64 * 72];    // [d][key]
  __shared__ __align__(16) ushort Pl[4][32 * 68];    // per-wave [qrow][key]

  const int tid  = threadIdx.x;
  const int lane = tid & 63, wave = tid >> 6;
  const int quad = lane >> 4, l15 = lane & 15;
  const int pair = blockIdx.x;                       // 0..7
  const int h = blockIdx.y, b = blockIdx.z;
  const int bh = b * NHEADS + h;
  const ushort* Qp  = Q  + (size_t)bh * SEQ * HDIM;
  const ushort* Kp  = K  + (size_t)bh * SEQ * HDIM;
  const ushort* VTp = VT + (size_t)bh * SEQ * HDIM;  // [d][s]

  const float slope2 = exp2f(-0.5f * (float)(h + 1)) * LOG2E;  // base-2 alibi
  const float c2 = 0.125f * LOG2E;                             // base-2 qk scale

  // staging chunk coords (2 chunks of 16B per thread per tile)
  const int sr0 = tid >> 3,        so0 = (tid & 7) * 8;
  const int sr1 = (tid + 256) >> 3, so1 = ((tid + 256) & 7) * 8;

  float basef[4];
#pragma unroll
  for (int ct = 0; ct < 4; ct++) basef[ct] = (float)(ct * 16 + l15);

  for (int qsel = 0; qsel < 2; qsel++) {
    const int qt = qsel ? (15 - pair) : pair;
    const int qbase = qt * 128;
    const int wq0 = qbase + wave * 32;
    const int wqmax = wq0 + 31;

    short8 qf[2][2];
#pragma unroll
    for (int mf = 0; mf < 2; mf++) {
      const ushort* qr = &Qp[(size_t)(wq0 + mf * 16 + l15) * HDIM];
      qf[mf][0] = *(const short8*)&qr[quad * 8];
      qf[mf][1] = *(const short8*)&qr[32 + quad * 8];
    }

    float m2[2][4], l_i[2][4], qrowf[2][4];
    floatx4 o_acc[2][4] = {};
    int qrow_c[2][4];
#pragma unroll
    for (int mf = 0; mf < 2; mf++)
#pragma unroll
      for (int r = 0; r < 4; r++) {
        m2[mf][r] = MASK_NEG; l_i[mf][r] = 0.f;
        qrow_c[mf][r] = wq0 + mf * 16 + quad * 4 + r;
        qrowf[mf][r] = (float)qrow_c[mf][r];
      }

    const int ntiles = 2 * qt + 2;

    // prefetch tile 0 into buffer 0
    {
      uint4 k0 = *(const uint4*)&Kp[(size_t)sr0 * HDIM + so0];
      uint4 v0 = *(const uint4*)&VTp[(size_t)sr0 * SEQ + so0];
      uint4 k1 = *(const uint4*)&Kp[(size_t)sr1 * HDIM + so1];
      uint4 v1 = *(const uint4*)&VTp[(size_t)sr1 * SEQ + so1];
      *(uint4*)&Kl[0][sr0 * 72 + so0] = k0;
      *(uint4*)&Vt[0][sr0 * 72 + so0] = v0;
      *(uint4*)&Kl[0][sr1 * 72 + so1] = k1;
      *(uint4*)&Vt[0][sr1 * 72 + so1] = v1;
    }
    __syncthreads();

    for (int kt = 0; kt < ntiles; kt++) {
      const int kb = kt * 64;
      const int cur = kt & 1;

      // issue prefetch loads for tile kt+1 (latency hidden behind compute)
      uint4 pk0, pv0, pk1, pv1;
      const bool more = (kt + 1 < ntiles);
      if (more) {
        const int kb2 = kb + 64;
        pk0 = *(const uint4*)&Kp[(size_t)(kb2 + sr0) * HDIM + so0];
        pv0 = *(const uint4*)&VTp[(size_t)sr0 * SEQ + kb2 + so0];
        pk1 = *(const uint4*)&Kp[(size_t)(kb2 + sr1) * HDIM + so1];
        pv1 = *(const uint4*)&VTp[(size_t)sr1 * SEQ + kb2 + so1];
      }

      if (kb <= wqmax) {
        const float kbf = (float)kb;
#pragma unroll
        for (int mf = 0; mf < 2; mf++) {
          floatx4 sc[4];
#pragma unroll
          for (int ct = 0; ct < 4; ct++) {
            short8 kf0 = *(const short8*)&Kl[cur][(ct * 16 + l15) * 72 + quad * 8];
            short8 kf1 = *(const short8*)&Kl[cur][(ct * 16 + l15) * 72 + 32 + quad * 8];
            floatx4 z = {};
            z = __builtin_amdgcn_mfma_f32_16x16x32_bf16(qf[mf][0], kf0, z, 0, 0, 0);
            sc[ct] = __builtin_amdgcn_mfma_f32_16x16x32_bf16(qf[mf][1], kf1, z, 0, 0, 0);
          }

          const bool needs_mask = (kb + 63 > wq0 + mf * 16);
          float rowmax[4] = {MASK_NEG, MASK_NEG, MASK_NEG, MASK_NEG};
#pragma unroll
          for (int ct = 0; ct < 4; ct++) {
            float keyf = kbf + basef[ct];
#pragma unroll
            for (int r = 0; r < 4; r++) {
              float relf = keyf - qrowf[mf][r];
              float v = fmaf(slope2, relf, sc[ct][r] * c2);
              if (needs_mask && relf > 0.f) v = MASK_NEG;
              sc[ct][r] = v;
              rowmax[r] = fmaxf(rowmax[r], v);
            }
          }
#pragma unroll
          for (int r = 0; r < 4; r++)
            for (int off = 1; off < 16; off <<= 1)
              rowmax[r] = fmaxf(rowmax[r], __shfl_xor(rowmax[r], off, 64));

          float alpha[4], rowsum[4];
#pragma unroll
          for (int r = 0; r < 4; r++) {
            float mn = fmaxf(m2[mf][r], rowmax[r]);
            alpha[r] = exp2f(m2[mf][r] - mn);
            m2[mf][r] = mn;
            rowsum[r] = 0.f;
          }
#pragma unroll
          for (int ct = 0; ct < 4; ct++)
#pragma unroll
            for (int r = 0; r < 4; r++) {
              float p = exp2f(sc[ct][r] - m2[mf][r]);
              rowsum[r] += p;
              Pl[wave][(mf * 16 + quad * 4 + r) * 68 + ct * 16 + l15] = f2bf(p);
            }
#pragma unroll
          for (int r = 0; r < 4; r++) {
            for (int off = 1; off < 16; off <<= 1)
              rowsum[r] += __shfl_xor(rowsum[r], off, 64);
            l_i[mf][r] = l_i[mf][r] * alpha[r] + rowsum[r];
          }
#pragma unroll
          for (int ct = 0; ct < 4; ct++)
#pragma unroll
            for (int r = 0; r < 4; r++) o_acc[mf][ct][r] *= alpha[r];
        }

        // O += P . V  (Pl per-wave; lgkmcnt orders write->read within wave)
#pragma unroll
        for (int ks = 0; ks < 2; ks++) {
          short8 vf[4];
#pragma unroll
          for (int ct = 0; ct < 4; ct++)
            vf[ct] = *(const short8*)&Vt[cur][(ct * 16 + l15) * 72 + ks * 32 + quad * 8];
#pragma unroll
          for (int mf = 0; mf < 2; mf++) {
            union { short8 v; uint2 u[2]; } pu;
            const ushort* pb = &Pl[wave][(mf * 16 + l15) * 68 + ks * 32 + quad * 8];
            pu.u[0] = *(const uint2*)(pb);
            pu.u[1] = *(const uint2*)(pb + 4);
#pragma unroll
            for (int ct = 0; ct < 4; ct++)
              o_acc[mf][ct] = __builtin_amdgcn_mfma_f32_16x16x32_bf16(pu.v, vf[ct], o_acc[mf][ct], 0, 0, 0);
          }
        }
      }

      // drain prefetch into the other buffer (readers of it finished last iter)
      if (more) {
        const int nxt = cur ^ 1;
        *(uint4*)&Kl[nxt][sr0 * 72 + so0] = pk0;
        *(uint4*)&Vt[nxt][sr0 * 72 + so0] = pv0;
        *(uint4*)&Kl[nxt][sr1 * 72 + so1] = pk1;
        *(uint4*)&Vt[nxt][sr1 * 72 + so1] = pv1;
      }
      __syncthreads();
    }

    // write (B,S,H,D) == (B,S,E)
#pragma unroll
    for (int mf = 0; mf < 2; mf++)
#pragma unroll
      for (int ct = 0; ct < 4; ct++)
#pragma unroll
        for (int r = 0; r < 4; r++) {
          int q = qrow_c[mf][r];
          float inv_l = 1.0f / fmaxf(l_i[mf][r], 1e-20f);
          float v = o_acc[mf][ct][r] * inv_l;
          Oout[(size_t)(b * SEQ + q) * EMBED + h * HDIM + ct * 16 + l15] = f2bf(v);
        }
  }
}

// ---------------------------------------------------------------------------
// ws layout (bytes):
//   flag @ 0          (1024)
//   xb   @ 1024       16777216
//   WTq  @ 16778240    6291456
//   WTo  @ 23069696    2097152
//   bqb  @ 25166848       6144
//   bob  @ 25172992       2048
//   Kw   @ 25175040   16777216
//   Vw   @ 41952256   16777216   (dead after transpose_v -> reused as Aw)
//   VT   @ 58729472   16777216   -> end 75506688
//   Qw   @ 75506688 if ws fits, else Q lives in d_out.
// ---------------------------------------------------------------------------
extern "C" void kernel_launch(void* const* d_in, const int* in_sizes, int n_in,
                              void* d_out, int out_size, void* d_ws, size_t ws_size,
                              hipStream_t stream) {
  const void* x     = d_in[0];
  const void* W_qkv = d_in[2];
  const void* b_qkv = d_in[3];
  const void* W_out = d_in[4];
  const void* b_out = d_in[5];

  char* ws = (char*)d_ws;
  int*    flag = (int*)(ws + 0);
  ushort* xb   = (ushort*)(ws + 1024);
  ushort* WTq  = (ushort*)(ws + 16778240);
  ushort* WTo  = (ushort*)(ws + 23069696);
  ushort* bqb  = (ushort*)(ws + 25166848);
  ushort* bob  = (ushort*)(ws + 25172992);
  ushort* Kw   = (ushort*)(ws + 25175040);
  ushort* Vw   = (ushort*)(ws + 41952256);
  ushort* VTw  = (ushort*)(ws + 58729472);
  ushort* Aw   = Vw;   // Vw dead after transpose_v
  ushort* Qw   = (ws_size >= (size_t)75506688 + 16777216)
                   ? (ushort*)(ws + 75506688)
                   : (ushort*)d_out;   // d_out as scratch: dead until final GEMM

  detect_dtype<<<1, 256, 0, stream>>>((const uint32_t*)x, flag);

  cvt_bf16<<<4096, 256, 0, stream>>>(x, xb, flag, BATCH * SEQ * EMBED);
  cvt_bf16<<<16, 256, 0, stream>>>(b_qkv, bqb, flag, 3 * EMBED);
  cvt_bf16<<<8, 256, 0, stream>>>(b_out, bob, flag, EMBED);

  transpose_cvt<<<dim3(3072 / 32, 1024 / 32), 256, 0, stream>>>(W_qkv, WTq, flag, 1024, 3072);
  transpose_cvt<<<dim3(1024 / 32, 1024 / 32), 256, 0, stream>>>(W_out, WTo, flag, 1024, 1024);

  gemm128<0><<<dim3(3072 / 128, 8192 / 128), 256, 0, stream>>>(
      xb, WTq, bqb, Qw, Kw, Vw, flag, BATCH * SEQ, 3 * EMBED, EMBED);

  transpose_v<<<dim3(SEQ / 32, HDIM / 32, BATCH * NHEADS), 256, 0, stream>>>(Vw, VTw);

  attn_kernel<<<dim3(SEQ / 256, NHEADS, BATCH), 256, 0, stream>>>(Qw, Kw, VTw, Aw);

  gemm128<1><<<dim3(1024 / 128, 8192 / 128), 256, 0, stream>>>(
      Aw, WTo, bob, (ushort*)d_out, nullptr, nullptr, flag, BATCH * SEQ, EMBED, EMBED);
}

// Round 6
// 381.679 us; speedup vs baseline: 1.5061x; 1.0369x over previous
//
#include <hip/hip_runtime.h>
#include <hip/hip_bf16.h>
#include <cstdint>
#include <cstddef>

#define BATCH  4
#define SEQ    2048
#define EMBED  1024
#define NHEADS 16
#define HDIM   64

typedef __attribute__((ext_vector_type(8))) short  short8;   // 8 x bf16 (4 VGPRs)
typedef __attribute__((ext_vector_type(4))) float  floatx4;  // MFMA C/D

#define MASK_NEG (-1.0e30f)   // finite "minus infinity": no inf-inf NaN paths
#define LOG2E    1.44269504f

__device__ __forceinline__ float bf2f(ushort u) {
  union { uint32_t i; float f; } v; v.i = ((uint32_t)u) << 16; return v.f;
}
__device__ __forceinline__ ushort f2bf(float f) {
  union { float f; uint32_t i; } v; v.f = f;
  uint32_t u = v.i;
  return (ushort)((u + 0x7fffu + ((u >> 16) & 1u)) >> 16);   // RNE
}
// packed RNE f32x2 -> bf16x2 (v_cvt_pk_bf16_f32 on gfx950)
__device__ __forceinline__ uint32_t f2bf_pk(float a, float b) {
  union { __hip_bfloat162 h; uint32_t u; } v;
  v.h = __float22bfloat162_rn(make_float2(a, b));
  return v.u;
}
// async global->LDS 16B/lane; LDS dst must be wave-uniform base + lane*16
__device__ __forceinline__ void gll16(const ushort* g, ushort* l) {
  __builtin_amdgcn_global_load_lds(
      (const __attribute__((address_space(1))) void*)g,
      (__attribute__((address_space(3))) void*)l, 16, 0, 0);
}

// ---------------------------------------------------------------------------
// Dtype detection (flag=1 bf16-packed, 0 fp32). Verified working since round 3.
// ---------------------------------------------------------------------------
__global__ __launch_bounds__(256) void detect_dtype(
    const uint32_t* __restrict__ x, int* __restrict__ flag) {
  __shared__ int sh[256];
  int tid = threadIdx.x;
  int c = 0;
#pragma unroll
  for (int i = 0; i < 16; i++) {
    uint32_t w = x[tid * 16 + i];
    uint32_t lo = w & 0xFFFFu;
    int e = (int)((lo >> 7) & 0xFF);
    if (lo == 0u || (e >= 100 && e <= 140)) c++;
  }
  sh[tid] = c;
  __syncthreads();
  if (tid == 0) {
    int s = 0;
    for (int i = 0; i < 256; i++) s += sh[i];
    *flag = (s >= 3500) ? 1 : 0;
  }
}

// vectorized x conversion: 4 elems/thread/step
__global__ __launch_bounds__(256) void cvt_bf16_v4(
    const void* __restrict__ in, ushort* __restrict__ out,
    const int* __restrict__ flag, int n4) {
  bool isbf = (*flag != 0);
  int stride = gridDim.x * 256;
  for (int i = blockIdx.x * 256 + threadIdx.x; i < n4; i += stride) {
    if (isbf) {
      ((uint2*)out)[i] = ((const uint2*)in)[i];
    } else {
      float4 f = ((const float4*)in)[i];
      uint2 o;
      o.x = f2bf_pk(f.x, f.y);
      o.y = f2bf_pk(f.z, f.w);
      ((uint2*)out)[i] = o;
    }
  }
}

__global__ __launch_bounds__(256) void cvt_bf16(
    const void* __restrict__ in, ushort* __restrict__ out,
    const int* __restrict__ flag, int n) {
  bool isbf = (*flag != 0);
  int stride = gridDim.x * 256;
  for (int i = blockIdx.x * 256 + threadIdx.x; i < n; i += stride)
    out[i] = isbf ? ((const ushort*)in)[i] : f2bf(((const float*)in)[i]);
}

__global__ __launch_bounds__(256) void transpose_cvt(
    const void* __restrict__ in, ushort* __restrict__ out,
    const int* __restrict__ flag, int R, int C) {
  bool isbf = (*flag != 0);
  __shared__ ushort tile[32][33];
  int bx = blockIdx.x * 32;
  int by = blockIdx.y * 32;
  int tx = threadIdx.x & 31, ty = threadIdx.x >> 5;
#pragma unroll
  for (int i = 0; i < 32; i += 8) {
    size_t idx = (size_t)(by + ty + i) * C + bx + tx;
    tile[ty + i][tx] = isbf ? ((const ushort*)in)[idx] : f2bf(((const float*)in)[idx]);
  }
  __syncthreads();
#pragma unroll
  for (int i = 0; i < 32; i += 8)
    out[(size_t)(bx + ty + i) * R + by + tx] = tile[tx][ty + i];
}

// ---------------------------------------------------------------------------
// Batched transpose: V (BH, S, D) bf16 -> VT (BH, D, S) bf16.
// ---------------------------------------------------------------------------
__global__ __launch_bounds__(256) void transpose_v(
    const ushort* __restrict__ in, ushort* __restrict__ out) {
  __shared__ ushort tile[32][33];
  int bh = blockIdx.z;
  int s0 = blockIdx.x * 32;
  int d0 = blockIdx.y * 32;
  int tx = threadIdx.x & 31, ty = threadIdx.x >> 5;
  const ushort* ip = in + (size_t)bh * SEQ * HDIM;
  ushort* op = out + (size_t)bh * SEQ * HDIM;
#pragma unroll
  for (int i = 0; i < 32; i += 8)
    tile[ty + i][tx] = ip[(size_t)(s0 + ty + i) * HDIM + d0 + tx];
  __syncthreads();
#pragma unroll
  for (int i = 0; i < 32; i += 8)
    op[(size_t)(d0 + ty + i) * SEQ + s0 + tx] = tile[tx][ty + i];
}

// ---------------------------------------------------------------------------
// GEMM, m97-style: global_load_lds width-16 staging (async HBM->LDS, no VGPR
// round-trip). LDS layout elem index = chunk*8 -> byte addr = tid*16 =
// wave-uniform base + lane*16 (required by global_load_lds).
// ---------------------------------------------------------------------------
template <int EPI>
__global__ __launch_bounds__(256) void gemm128(
    const ushort* __restrict__ A, const ushort* __restrict__ BT,
    const ushort* __restrict__ bias,
    ushort* __restrict__ out0, ushort* __restrict__ out1, ushort* __restrict__ out2,
    const int* __restrict__ flag,
    int M, int N, int K) {
  __shared__ __align__(16) ushort Al[128 * 32];
  __shared__ __align__(16) ushort Bl[128 * 32];

  const int tid  = threadIdx.x;
  const int lane = tid & 63, wave = tid >> 6;
  const int quad = lane >> 4, l15 = lane & 15;
  const int wm = wave >> 1, wn = wave & 1;
  const int rowA0 = blockIdx.y * 128;
  const int colB0 = blockIdx.x * 128;

  floatx4 acc[4][4] = {};

  const int r0 = tid >> 2, o0 = (tid & 3) * 8;   // chunk c -> row c>>2, off (c&3)*8
  const int r1 = r0 + 64;                        // chunk c+256

  for (int kk = 0; kk < K; kk += 32) {
    __syncthreads();
    gll16(&A [(size_t)(rowA0 + r0) * K + kk + o0], &Al[tid * 8]);
    gll16(&A [(size_t)(rowA0 + r1) * K + kk + o0], &Al[(tid + 256) * 8]);
    gll16(&BT[(size_t)(colB0 + r0) * K + kk + o0], &Bl[tid * 8]);
    gll16(&BT[(size_t)(colB0 + r1) * K + kk + o0], &Bl[(tid + 256) * 8]);
    __syncthreads();

    short8 af[4], bf[4];
#pragma unroll
    for (int mt = 0; mt < 4; mt++)
      af[mt] = *(const short8*)&Al[(wm * 64 + mt * 16 + l15) * 32 + quad * 8];
#pragma unroll
    for (int nt = 0; nt < 4; nt++)
      bf[nt] = *(const short8*)&Bl[(wn * 64 + nt * 16 + l15) * 32 + quad * 8];
#pragma unroll
    for (int mt = 0; mt < 4; mt++)
#pragma unroll
      for (int nt = 0; nt < 4; nt++)
        acc[mt][nt] = __builtin_amdgcn_mfma_f32_16x16x32_bf16(af[mt], bf[nt], acc[mt][nt], 0, 0, 0);
  }

  const bool isbf = (EPI == 1) ? (*flag != 0) : true;

#pragma unroll
  for (int mt = 0; mt < 4; mt++)
#pragma unroll
    for (int nt = 0; nt < 4; nt++)
#pragma unroll
      for (int r = 0; r < 4; r++) {
        int row = rowA0 + wm * 64 + mt * 16 + quad * 4 + r;
        int col = colB0 + wn * 64 + nt * 16 + l15;
        float v = acc[mt][nt][r] + bf2f(bias[col]);
        if (EPI == 0) {
          int three = col >> 10, rem = col & 1023, h = rem >> 6, d = rem & 63;
          int b = row >> 11, s = row & 2047;
          ushort* dst = (three == 0) ? out0 : (three == 1) ? out1 : out2;
          dst[((size_t)(b * NHEADS + h) * SEQ + s) * HDIM + d] = f2bf(v);
        } else {
          if (isbf) out0[(size_t)row * N + col] = f2bf(v);
          else      ((float*)out0)[(size_t)row * N + col] = v;
        }
      }
}

// ---------------------------------------------------------------------------
// Flash attention v4. Q,K (B,H,S,D); VT (B,H,D,S); out (B,S,H,D), all bf16.
//  - Diagonal pairing (perfect balance, grid 512 = 2 blocks/CU).
//  - Double-buffered K/V staging (reg prefetch), ONE barrier/iter.
//  - Slope-folded ALiBi: -slope*qrow is a per-row softmax-invariant constant,
//    dropped; only slope2*key added (hoisted per-ct constant).
//  - Packed bf16 P conversion (v_cvt_pk_bf16_f32).
// ---------------------------------------------------------------------------
__global__ __launch_bounds__(256, 2) void attn_kernel(
    const ushort* __restrict__ Q, const ushort* __restrict__ K,
    const ushort* __restrict__ VT, ushort* __restrict__ Oout) {
  __shared__ __align__(16) ushort Kl[2][64 * 72];    // [key][d]
  __shared__ __align__(16) ushort Vt[2][64 * 72];    // [d][key]
  __shared__ __align__(16) ushort Pl[4][32 * 68];    // per-wave [qrow][key]

  const int tid  = threadIdx.x;
  const int lane = tid & 63, wave = tid >> 6;
  const int quad = lane >> 4, l15 = lane & 15;
  const int pair = blockIdx.x;                       // 0..7
  const int h = blockIdx.y, b = blockIdx.z;
  const int bh = b * NHEADS + h;
  const ushort* Qp  = Q  + (size_t)bh * SEQ * HDIM;
  const ushort* Kp  = K  + (size_t)bh * SEQ * HDIM;
  const ushort* VTp = VT + (size_t)bh * SEQ * HDIM;  // [d][s]

  const float slope2 = exp2f(-0.5f * (float)(h + 1)) * LOG2E;  // base-2 alibi
  const float c2 = 0.125f * LOG2E;                             // base-2 qk scale

  const int sr0 = tid >> 3,         so0 = (tid & 7) * 8;
  const int sr1 = (tid + 256) >> 3, so1 = ((tid + 256) & 7) * 8;

  float basef[4];
#pragma unroll
  for (int ct = 0; ct < 4; ct++) basef[ct] = (float)(ct * 16 + l15);

  for (int qsel = 0; qsel < 2; qsel++) {
    const int qt = qsel ? (15 - pair) : pair;
    const int qbase = qt * 128;
    const int wq0 = qbase + wave * 32;
    const int wqmax = wq0 + 31;

    short8 qf[2][2];
#pragma unroll
    for (int mf = 0; mf < 2; mf++) {
      const ushort* qr = &Qp[(size_t)(wq0 + mf * 16 + l15) * HDIM];
      qf[mf][0] = *(const short8*)&qr[quad * 8];
      qf[mf][1] = *(const short8*)&qr[32 + quad * 8];
    }

    float m2[2][4], l_i[2][4], qrowf[2][4];
    floatx4 o_acc[2][4] = {};
    int qrow_c[2][4];
#pragma unroll
    for (int mf = 0; mf < 2; mf++)
#pragma unroll
      for (int r = 0; r < 4; r++) {
        m2[mf][r] = MASK_NEG; l_i[mf][r] = 0.f;
        qrow_c[mf][r] = wq0 + mf * 16 + quad * 4 + r;
        qrowf[mf][r] = (float)qrow_c[mf][r];
      }

    const int ntiles = 2 * qt + 2;

    // prefetch tile 0 into buffer 0
    {
      uint4 k0 = *(const uint4*)&Kp[(size_t)sr0 * HDIM + so0];
      uint4 v0 = *(const uint4*)&VTp[(size_t)sr0 * SEQ + so0];
      uint4 k1 = *(const uint4*)&Kp[(size_t)sr1 * HDIM + so1];
      uint4 v1 = *(const uint4*)&VTp[(size_t)sr1 * SEQ + so1];
      *(uint4*)&Kl[0][sr0 * 72 + so0] = k0;
      *(uint4*)&Vt[0][sr0 * 72 + so0] = v0;
      *(uint4*)&Kl[0][sr1 * 72 + so1] = k1;
      *(uint4*)&Vt[0][sr1 * 72 + so1] = v1;
    }
    __syncthreads();

    for (int kt = 0; kt < ntiles; kt++) {
      const int kb = kt * 64;
      const int cur = kt & 1;

      uint4 pk0, pv0, pk1, pv1;
      const bool more = (kt + 1 < ntiles);
      if (more) {
        const int kb2 = kb + 64;
        pk0 = *(const uint4*)&Kp[(size_t)(kb2 + sr0) * HDIM + so0];
        pv0 = *(const uint4*)&VTp[(size_t)sr0 * SEQ + kb2 + so0];
        pk1 = *(const uint4*)&Kp[(size_t)(kb2 + sr1) * HDIM + so1];
        pv1 = *(const uint4*)&VTp[(size_t)sr1 * SEQ + kb2 + so1];
      }

      if (kb <= wqmax) {
        const float kbf = (float)kb;
        float keyf4[4], keyterm[4];
#pragma unroll
        for (int ct = 0; ct < 4; ct++) {
          keyf4[ct] = kbf + basef[ct];
          keyterm[ct] = slope2 * keyf4[ct];
        }
#pragma unroll
        for (int mf = 0; mf < 2; mf++) {
          floatx4 sc[4];
#pragma unroll
          for (int ct = 0; ct < 4; ct++) {
            short8 kf0 = *(const short8*)&Kl[cur][(ct * 16 + l15) * 72 + quad * 8];
            short8 kf1 = *(const short8*)&Kl[cur][(ct * 16 + l15) * 72 + 32 + quad * 8];
            floatx4 z = {};
            z = __builtin_amdgcn_mfma_f32_16x16x32_bf16(qf[mf][0], kf0, z, 0, 0, 0);
            sc[ct] = __builtin_amdgcn_mfma_f32_16x16x32_bf16(qf[mf][1], kf1, z, 0, 0, 0);
          }

          const bool needs_mask = (kb + 63 > wq0 + mf * 16);
          float rowmax[4] = {MASK_NEG, MASK_NEG, MASK_NEG, MASK_NEG};
#pragma unroll
          for (int ct = 0; ct < 4; ct++)
#pragma unroll
            for (int r = 0; r < 4; r++) {
              float v = fmaf(sc[ct][r], c2, keyterm[ct]);
              if (needs_mask && keyf4[ct] > qrowf[mf][r]) v = MASK_NEG;
              sc[ct][r] = v;
              rowmax[r] = fmaxf(rowmax[r], v);
            }
#pragma unroll
          for (int r = 0; r < 4; r++)
            for (int off = 1; off < 16; off <<= 1)
              rowmax[r] = fmaxf(rowmax[r], __shfl_xor(rowmax[r], off, 64));

          float alpha[4];
#pragma unroll
          for (int r = 0; r < 4; r++) {
            float mn = fmaxf(m2[mf][r], rowmax[r]);
            alpha[r] = exp2f(m2[mf][r] - mn);
            m2[mf][r] = mn;
          }
          float rowsum[4];
#pragma unroll
          for (int r = 0; r < 4; r++) {
            float m = m2[mf][r];
            float p0 = exp2f(sc[0][r] - m), p1 = exp2f(sc[1][r] - m);
            float p2 = exp2f(sc[2][r] - m), p3 = exp2f(sc[3][r] - m);
            rowsum[r] = (p0 + p1) + (p2 + p3);
            uint32_t ua = f2bf_pk(p0, p1);
            uint32_t ub = f2bf_pk(p2, p3);
            ushort* prow = &Pl[wave][(mf * 16 + quad * 4 + r) * 68 + l15];
            prow[0]  = (ushort)(ua & 0xFFFFu);
            prow[16] = (ushort)(ua >> 16);
            prow[32] = (ushort)(ub & 0xFFFFu);
            prow[48] = (ushort)(ub >> 16);
          }
#pragma unroll
          for (int r = 0; r < 4; r++) {
            for (int off = 1; off < 16; off <<= 1)
              rowsum[r] += __shfl_xor(rowsum[r], off, 64);
            l_i[mf][r] = l_i[mf][r] * alpha[r] + rowsum[r];
          }
#pragma unroll
          for (int ct = 0; ct < 4; ct++)
#pragma unroll
            for (int r = 0; r < 4; r++) o_acc[mf][ct][r] *= alpha[r];
        }

        // O += P . V  (Pl per-wave; lgkmcnt orders write->read within wave)
#pragma unroll
        for (int ks = 0; ks < 2; ks++) {
          short8 vf[4];
#pragma unroll
          for (int ct = 0; ct < 4; ct++)
            vf[ct] = *(const short8*)&Vt[cur][(ct * 16 + l15) * 72 + ks * 32 + quad * 8];
#pragma unroll
          for (int mf = 0; mf < 2; mf++) {
            union { short8 v; uint2 u[2]; } pu;
            const ushort* pb = &Pl[wave][(mf * 16 + l15) * 68 + ks * 32 + quad * 8];
            pu.u[0] = *(const uint2*)(pb);
            pu.u[1] = *(const uint2*)(pb + 4);
#pragma unroll
            for (int ct = 0; ct < 4; ct++)
              o_acc[mf][ct] = __builtin_amdgcn_mfma_f32_16x16x32_bf16(pu.v, vf[ct], o_acc[mf][ct], 0, 0, 0);
          }
        }
      }

      if (more) {
        const int nxt = cur ^ 1;
        *(uint4*)&Kl[nxt][sr0 * 72 + so0] = pk0;
        *(uint4*)&Vt[nxt][sr0 * 72 + so0] = pv0;
        *(uint4*)&Kl[nxt][sr1 * 72 + so1] = pk1;
        *(uint4*)&Vt[nxt][sr1 * 72 + so1] = pv1;
      }
      __syncthreads();
    }

    // write (B,S,H,D) == (B,S,E)
#pragma unroll
    for (int mf = 0; mf < 2; mf++)
#pragma unroll
      for (int ct = 0; ct < 4; ct++)
#pragma unroll
        for (int r = 0; r < 4; r++) {
          int q = qrow_c[mf][r];
          float inv_l = 1.0f / fmaxf(l_i[mf][r], 1e-20f);
          float v = o_acc[mf][ct][r] * inv_l;
          Oout[(size_t)(b * SEQ + q) * EMBED + h * HDIM + ct * 16 + l15] = f2bf(v);
        }
  }
}

// ---------------------------------------------------------------------------
// ws layout (bytes):
//   flag @ 0          (1024)
//   xb   @ 1024       16777216
//   WTq  @ 16778240    6291456
//   WTo  @ 23069696    2097152
//   bqb  @ 25166848       6144
//   bob  @ 25172992       2048
//   Kw   @ 25175040   16777216
//   Vw   @ 41952256   16777216   (dead after transpose_v -> reused as Aw)
//   VT   @ 58729472   16777216   -> end 75506688
//   Qw   @ 75506688 if ws fits, else Q lives in d_out.
// ---------------------------------------------------------------------------
extern "C" void kernel_launch(void* const* d_in, const int* in_sizes, int n_in,
                              void* d_out, int out_size, void* d_ws, size_t ws_size,
                              hipStream_t stream) {
  const void* x     = d_in[0];
  const void* W_qkv = d_in[2];
  const void* b_qkv = d_in[3];
  const void* W_out = d_in[4];
  const void* b_out = d_in[5];

  char* ws = (char*)d_ws;
  int*    flag = (int*)(ws + 0);
  ushort* xb   = (ushort*)(ws + 1024);
  ushort* WTq  = (ushort*)(ws + 16778240);
  ushort* WTo  = (ushort*)(ws + 23069696);
  ushort* bqb  = (ushort*)(ws + 25166848);
  ushort* bob  = (ushort*)(ws + 25172992);
  ushort* Kw   = (ushort*)(ws + 25175040);
  ushort* Vw   = (ushort*)(ws + 41952256);
  ushort* VTw  = (ushort*)(ws + 58729472);
  ushort* Aw   = Vw;   // Vw dead after transpose_v
  ushort* Qw   = (ws_size >= (size_t)75506688 + 16777216)
                   ? (ushort*)(ws + 75506688)
                   : (ushort*)d_out;   // d_out as scratch: dead until final GEMM

  detect_dtype<<<1, 256, 0, stream>>>((const uint32_t*)x, flag);

  cvt_bf16_v4<<<2048, 256, 0, stream>>>(x, xb, flag, BATCH * SEQ * EMBED / 4);
  cvt_bf16<<<16, 256, 0, stream>>>(b_qkv, bqb, flag, 3 * EMBED);
  cvt_bf16<<<8, 256, 0, stream>>>(b_out, bob, flag, EMBED);

  transpose_cvt<<<dim3(3072 / 32, 1024 / 32), 256, 0, stream>>>(W_qkv, WTq, flag, 1024, 3072);
  transpose_cvt<<<dim3(1024 / 32, 1024 / 32), 256, 0, stream>>>(W_out, WTo, flag, 1024, 1024);

  gemm128<0><<<dim3(3072 / 128, 8192 / 128), 256, 0, stream>>>(
      xb, WTq, bqb, Qw, Kw, Vw, flag, BATCH * SEQ, 3 * EMBED, EMBED);

  transpose_v<<<dim3(SEQ / 32, HDIM / 32, BATCH * NHEADS), 256, 0, stream>>>(Vw, VTw);

  attn_kernel<<<dim3(SEQ / 256, NHEADS, BATCH), 256, 0, stream>>>(Qw, Kw, VTw, Aw);

  gemm128<1><<<dim3(1024 / 128, 8192 / 128), 256, 0, stream>>>(
      Aw, WTo, bob, (ushort*)d_out, nullptr, nullptr, flag, BATCH * SEQ, EMBED, EMBED);
}

// Round 7
// 380.422 us; speedup vs baseline: 1.5110x; 1.0033x over previous
//
#include <hip/hip_runtime.h>
#include <hip/hip_bf16.h>
#include <cstdint>
#include <cstddef>

#define BATCH  4
#define SEQ    2048
#define EMBED  1024
#define NHEADS 16
#define HDIM   64

typedef __attribute__((ext_vector_type(8))) short  short8;   // 8 x bf16 (4 VGPRs)
typedef __attribute__((ext_vector_type(4))) float  floatx4;  // MFMA C/D

#define MASK_NEG (-1.0e30f)   // finite "minus infinity": no inf-inf NaN paths
#define LOG2E    1.44269504f

__device__ __forceinline__ float bf2f(ushort u) {
  union { uint32_t i; float f; } v; v.i = ((uint32_t)u) << 16; return v.f;
}
__device__ __forceinline__ ushort f2bf(float f) {
  union { float f; uint32_t i; } v; v.f = f;
  uint32_t u = v.i;
  return (ushort)((u + 0x7fffu + ((u >> 16) & 1u)) >> 16);   // RNE
}
// packed RNE f32x2 -> bf16x2 (v_cvt_pk_bf16_f32 on gfx950)
__device__ __forceinline__ uint32_t f2bf_pk(float a, float b) {
  union { __hip_bfloat162 h; uint32_t u; } v;
  v.h = __float22bfloat162_rn(make_float2(a, b));
  return v.u;
}
// async global->LDS 16B/lane; LDS dst must be wave-uniform base + lane*16
__device__ __forceinline__ void gll16(const ushort* g, ushort* l) {
  __builtin_amdgcn_global_load_lds(
      (const __attribute__((address_space(1))) void*)g,
      (__attribute__((address_space(3))) void*)l, 16, 0, 0);
}

// ---------------------------------------------------------------------------
// Dtype detection (flag=1 bf16-packed, 0 fp32). Verified working since round 3.
// ---------------------------------------------------------------------------
__global__ __launch_bounds__(256) void detect_dtype(
    const uint32_t* __restrict__ x, int* __restrict__ flag) {
  __shared__ int sh[256];
  int tid = threadIdx.x;
  int c = 0;
#pragma unroll
  for (int i = 0; i < 16; i++) {
    uint32_t w = x[tid * 16 + i];
    uint32_t lo = w & 0xFFFFu;
    int e = (int)((lo >> 7) & 0xFF);
    if (lo == 0u || (e >= 100 && e <= 140)) c++;
  }
  sh[tid] = c;
  __syncthreads();
  if (tid == 0) {
    int s = 0;
    for (int i = 0; i < 256; i++) s += sh[i];
    *flag = (s >= 3500) ? 1 : 0;
  }
}

// vectorized x conversion: 4 elems/thread/step
__global__ __launch_bounds__(256) void cvt_bf16_v4(
    const void* __restrict__ in, ushort* __restrict__ out,
    const int* __restrict__ flag, int n4) {
  bool isbf = (*flag != 0);
  int stride = gridDim.x * 256;
  for (int i = blockIdx.x * 256 + threadIdx.x; i < n4; i += stride) {
    if (isbf) {
      ((uint2*)out)[i] = ((const uint2*)in)[i];
    } else {
      float4 f = ((const float4*)in)[i];
      uint2 o;
      o.x = f2bf_pk(f.x, f.y);
      o.y = f2bf_pk(f.z, f.w);
      ((uint2*)out)[i] = o;
    }
  }
}

// both biases in one launch: i<3072 -> bqb, else bob
__global__ __launch_bounds__(256) void cvt_biases(
    const void* __restrict__ bq, const void* __restrict__ bo,
    ushort* __restrict__ bqb, ushort* __restrict__ bob,
    const int* __restrict__ flag) {
  bool isbf = (*flag != 0);
  int i = blockIdx.x * 256 + threadIdx.x;
  if (i < 3 * EMBED) {
    bqb[i] = isbf ? ((const ushort*)bq)[i] : f2bf(((const float*)bq)[i]);
  } else {
    int j = i - 3 * EMBED;
    bob[j] = isbf ? ((const ushort*)bo)[j] : f2bf(((const float*)bo)[j]);
  }
}

__global__ __launch_bounds__(256) void transpose_cvt(
    const void* __restrict__ in, ushort* __restrict__ out,
    const int* __restrict__ flag, int R, int C) {
  bool isbf = (*flag != 0);
  __shared__ ushort tile[32][33];
  int bx = blockIdx.x * 32;
  int by = blockIdx.y * 32;
  int tx = threadIdx.x & 31, ty = threadIdx.x >> 5;
#pragma unroll
  for (int i = 0; i < 32; i += 8) {
    size_t idx = (size_t)(by + ty + i) * C + bx + tx;
    tile[ty + i][tx] = isbf ? ((const ushort*)in)[idx] : f2bf(((const float*)in)[idx]);
  }
  __syncthreads();
#pragma unroll
  for (int i = 0; i < 32; i += 8)
    out[(size_t)(bx + ty + i) * R + by + tx] = tile[tx][ty + i];
}

// ---------------------------------------------------------------------------
// Batched transpose: V (BH, S, D) bf16 -> VT (BH, D, S) bf16.
// ---------------------------------------------------------------------------
__global__ __launch_bounds__(256) void transpose_v(
    const ushort* __restrict__ in, ushort* __restrict__ out) {
  __shared__ ushort tile[32][33];
  int bh = blockIdx.z;
  int s0 = blockIdx.x * 32;
  int d0 = blockIdx.y * 32;
  int tx = threadIdx.x & 31, ty = threadIdx.x >> 5;
  const ushort* ip = in + (size_t)bh * SEQ * HDIM;
  ushort* op = out + (size_t)bh * SEQ * HDIM;
#pragma unroll
  for (int i = 0; i < 32; i += 8)
    tile[ty + i][tx] = ip[(size_t)(s0 + ty + i) * HDIM + d0 + tx];
  __syncthreads();
#pragma unroll
  for (int i = 0; i < 32; i += 8)
    op[(size_t)(d0 + ty + i) * SEQ + s0 + tx] = tile[tx][ty + i];
}

// ---------------------------------------------------------------------------
// GEMM (m97-style, unchanged from passing round 6).
// ---------------------------------------------------------------------------
template <int EPI>
__global__ __launch_bounds__(256) void gemm128(
    const ushort* __restrict__ A, const ushort* __restrict__ BT,
    const ushort* __restrict__ bias,
    ushort* __restrict__ out0, ushort* __restrict__ out1, ushort* __restrict__ out2,
    const int* __restrict__ flag,
    int M, int N, int K) {
  __shared__ __align__(16) ushort Al[128 * 32];
  __shared__ __align__(16) ushort Bl[128 * 32];

  const int tid  = threadIdx.x;
  const int lane = tid & 63, wave = tid >> 6;
  const int quad = lane >> 4, l15 = lane & 15;
  const int wm = wave >> 1, wn = wave & 1;
  const int rowA0 = blockIdx.y * 128;
  const int colB0 = blockIdx.x * 128;

  floatx4 acc[4][4] = {};

  const int r0 = tid >> 2, o0 = (tid & 3) * 8;
  const int r1 = r0 + 64;

  for (int kk = 0; kk < K; kk += 32) {
    __syncthreads();
    gll16(&A [(size_t)(rowA0 + r0) * K + kk + o0], &Al[tid * 8]);
    gll16(&A [(size_t)(rowA0 + r1) * K + kk + o0], &Al[(tid + 256) * 8]);
    gll16(&BT[(size_t)(colB0 + r0) * K + kk + o0], &Bl[tid * 8]);
    gll16(&BT[(size_t)(colB0 + r1) * K + kk + o0], &Bl[(tid + 256) * 8]);
    __syncthreads();

    short8 af[4], bf[4];
#pragma unroll
    for (int mt = 0; mt < 4; mt++)
      af[mt] = *(const short8*)&Al[(wm * 64 + mt * 16 + l15) * 32 + quad * 8];
#pragma unroll
    for (int nt = 0; nt < 4; nt++)
      bf[nt] = *(const short8*)&Bl[(wn * 64 + nt * 16 + l15) * 32 + quad * 8];
#pragma unroll
    for (int mt = 0; mt < 4; mt++)
#pragma unroll
      for (int nt = 0; nt < 4; nt++)
        acc[mt][nt] = __builtin_amdgcn_mfma_f32_16x16x32_bf16(af[mt], bf[nt], acc[mt][nt], 0, 0, 0);
  }

  const bool isbf = (EPI == 1) ? (*flag != 0) : true;

#pragma unroll
  for (int mt = 0; mt < 4; mt++)
#pragma unroll
    for (int nt = 0; nt < 4; nt++)
#pragma unroll
      for (int r = 0; r < 4; r++) {
        int row = rowA0 + wm * 64 + mt * 16 + quad * 4 + r;
        int col = colB0 + wn * 64 + nt * 16 + l15;
        float v = acc[mt][nt][r] + bf2f(bias[col]);
        if (EPI == 0) {
          int three = col >> 10, rem = col & 1023, h = rem >> 6, d = rem & 63;
          int b = row >> 11, s = row & 2047;
          ushort* dst = (three == 0) ? out0 : (three == 1) ? out1 : out2;
          dst[((size_t)(b * NHEADS + h) * SEQ + s) * HDIM + d] = f2bf(v);
        } else {
          if (isbf) out0[(size_t)row * N + col] = f2bf(v);
          else      ((float*)out0)[(size_t)row * N + col] = v;
        }
      }
}

// ---------------------------------------------------------------------------
// Flash attention v5: TRANSPOSED scores (S^T = K·Q^T) so each lane owns one
// softmax row per mf; 128-key tiles; single LDS K/V buffer + register
// prefetch; diagonal pairing {i, 15-i} (17 tiles/block, perfectly balanced,
// grid 512 = 2 blocks/CU).
//   QK: A=K-frag, B=Q-frag (same LDS patterns as before, operands swapped).
//   S^T C-layout: row=key(quad*4+r per kct), col=lane l15 = q-row.
//   Softmax: in-lane tree (32 vals) + 2 shuffles (xor16/32 across quads).
//   P store: 4 consecutive keys/lane -> packed ds_write_b64; PV A-frag reads
//   P as ds_read_b128. PV unchanged: O = P·V with B=Vt.
// ---------------------------------------------------------------------------
__global__ __launch_bounds__(256, 2) void attn_kernel(
    const ushort* __restrict__ Q, const ushort* __restrict__ K,
    const ushort* __restrict__ VT, ushort* __restrict__ Oout) {
  __shared__ __align__(16) ushort Kl[128 * 72];      // [key][d]
  __shared__ __align__(16) ushort Vt[64 * 136];      // [d][key]
  __shared__ __align__(16) ushort Pl[4][32 * 136];   // per-wave [qrow][key]

  const int tid  = threadIdx.x;
  const int lane = tid & 63, wave = tid >> 6;
  const int quad = lane >> 4, l15 = lane & 15;
  const int pair = blockIdx.x;                       // 0..7
  const int h = blockIdx.y, b = blockIdx.z;
  const int bh = b * NHEADS + h;
  const ushort* Qp  = Q  + (size_t)bh * SEQ * HDIM;
  const ushort* Kp  = K  + (size_t)bh * SEQ * HDIM;
  const ushort* VTp = VT + (size_t)bh * SEQ * HDIM;  // [d][s]

  const float slope2 = exp2f(-0.5f * (float)(h + 1)) * LOG2E;
  const float c2 = 0.125f * LOG2E;
  float rt[4];
#pragma unroll
  for (int r = 0; r < 4; r++) rt[r] = slope2 * (float)r;

  const int krow = tid >> 3, koff = (tid & 7) * 8;    // K tile: 128 x 64
  const int vrow = tid >> 4, voff = (tid & 15) * 8;   // V tile: 64 x 128

  for (int qsel = 0; qsel < 2; qsel++) {
    const int qt = qsel ? (15 - pair) : pair;
    const int qbase = qt * 128;
    const int wq0 = qbase + wave * 32;

    short8 qf[2][2];
#pragma unroll
    for (int mf = 0; mf < 2; mf++) {
      const ushort* qr = &Qp[(size_t)(wq0 + mf * 16 + l15) * HDIM];
      qf[mf][0] = *(const short8*)&qr[quad * 8];
      qf[mf][1] = *(const short8*)&qr[32 + quad * 8];
    }

    float m2s[2] = {MASK_NEG, MASK_NEG}, lis[2] = {0.f, 0.f};
    float qrowf[2];
#pragma unroll
    for (int mf = 0; mf < 2; mf++) qrowf[mf] = (float)(wq0 + mf * 16 + l15);
    floatx4 o_acc[2][4] = {};

    // tile 0 into LDS (barrier first: protect from previous qsel's readers)
    uint4 pk[4], pv[4];
#pragma unroll
    for (int j = 0; j < 4; j++) {
      pk[j] = *(const uint4*)&Kp[(size_t)(krow + 32 * j) * HDIM + koff];
      pv[j] = *(const uint4*)&VTp[(size_t)(vrow + 16 * j) * SEQ + voff];
    }
    __syncthreads();
#pragma unroll
    for (int j = 0; j < 4; j++) {
      *(uint4*)&Kl[(krow + 32 * j) * 72 + koff]  = pk[j];
      *(uint4*)&Vt[(vrow + 16 * j) * 136 + voff] = pv[j];
    }
    __syncthreads();

    for (int kt = 0; kt <= qt; kt++) {
      const int kb = kt * 128;
      const bool more = (kt < qt);
      if (more) {
        const int kb2 = kb + 128;
#pragma unroll
        for (int j = 0; j < 4; j++) {
          pk[j] = *(const uint4*)&Kp[(size_t)(kb2 + krow + 32 * j) * HDIM + koff];
          pv[j] = *(const uint4*)&VTp[(size_t)(vrow + 16 * j) * SEQ + kb2 + voff];
        }
      }

      // S^T = K . Q^T  (row=key, col=q)
      floatx4 s0[8], s1[8];
#pragma unroll
      for (int kct = 0; kct < 8; kct++) {
        short8 a0 = *(const short8*)&Kl[(kct * 16 + l15) * 72 + quad * 8];
        short8 a1 = *(const short8*)&Kl[(kct * 16 + l15) * 72 + 32 + quad * 8];
        floatx4 z0 = {}, z1 = {};
        z0 = __builtin_amdgcn_mfma_f32_16x16x32_bf16(a0, qf[0][0], z0, 0, 0, 0);
        s0[kct] = __builtin_amdgcn_mfma_f32_16x16x32_bf16(a1, qf[0][1], z0, 0, 0, 0);
        z1 = __builtin_amdgcn_mfma_f32_16x16x32_bf16(a0, qf[1][0], z1, 0, 0, 0);
        s1[kct] = __builtin_amdgcn_mfma_f32_16x16x32_bf16(a1, qf[1][1], z1, 0, 0, 0);
      }

      const bool needs_mask = (kt == qt);   // wave-uniform: only diagonal tile
#pragma unroll
      for (int mf = 0; mf < 2; mf++) {
        floatx4* sm = mf ? s1 : s0;
        // scale + alibi(+mask) + in-lane max (lane owns row q = qrowf[mf])
        float mloc = MASK_NEG;
#pragma unroll
        for (int kct = 0; kct < 8; kct++) {
          float keyb = (float)(kb + kct * 16 + quad * 4);
          float base = slope2 * keyb;
#pragma unroll
          for (int r = 0; r < 4; r++) {
            float v = fmaf(sm[kct][r], c2, base + rt[r]);
            if (needs_mask && (keyb + (float)r > qrowf[mf])) v = MASK_NEG;
            sm[kct][r] = v;
            mloc = fmaxf(mloc, v);
          }
        }
        mloc = fmaxf(mloc, __shfl_xor(mloc, 16, 64));
        mloc = fmaxf(mloc, __shfl_xor(mloc, 32, 64));

        float mn = fmaxf(m2s[mf], mloc);
        float al = exp2f(m2s[mf] - mn);
        m2s[mf] = mn;

        float rs = 0.f;
#pragma unroll
        for (int kct = 0; kct < 8; kct++) {
          float p0 = exp2f(sm[kct][0] - mn), p1 = exp2f(sm[kct][1] - mn);
          float p2 = exp2f(sm[kct][2] - mn), p3 = exp2f(sm[kct][3] - mn);
          rs += (p0 + p1) + (p2 + p3);
          uint2 pw;
          pw.x = f2bf_pk(p0, p1);
          pw.y = f2bf_pk(p2, p3);
          *(uint2*)&Pl[wave][(mf * 16 + l15) * 136 + kct * 16 + quad * 4] = pw;
        }
        rs += __shfl_xor(rs, 16, 64);
        rs += __shfl_xor(rs, 32, 64);
        lis[mf] = lis[mf] * al + rs;

        float alr[4];
#pragma unroll
        for (int r = 0; r < 4; r++) alr[r] = __shfl(al, quad * 4 + r, 16);
#pragma unroll
        for (int ct = 0; ct < 4; ct++)
#pragma unroll
          for (int r = 0; r < 4; r++) o_acc[mf][ct][r] *= alr[r];
      }

      // O += P . V  (A = P row-major [q][key] b128, B = Vt; per-wave Pl)
#pragma unroll
      for (int ks = 0; ks < 4; ks++) {
        short8 vf[4];
#pragma unroll
        for (int ct = 0; ct < 4; ct++)
          vf[ct] = *(const short8*)&Vt[(ct * 16 + l15) * 136 + ks * 32 + quad * 8];
#pragma unroll
        for (int mf = 0; mf < 2; mf++) {
          short8 pf = *(const short8*)&Pl[wave][(mf * 16 + l15) * 136 + ks * 32 + quad * 8];
#pragma unroll
          for (int ct = 0; ct < 4; ct++)
            o_acc[mf][ct] = __builtin_amdgcn_mfma_f32_16x16x32_bf16(pf, vf[ct], o_acc[mf][ct], 0, 0, 0);
        }
      }

      if (more) {
        __syncthreads();   // all waves done reading Kl/Vt
#pragma unroll
        for (int j = 0; j < 4; j++) {
          *(uint4*)&Kl[(krow + 32 * j) * 72 + koff]  = pk[j];
          *(uint4*)&Vt[(vrow + 16 * j) * 136 + voff] = pv[j];
        }
        __syncthreads();
      }
    }

    // epilogue: O rows q = wq0+mf*16+quad*4+r, cols d = ct*16+l15
#pragma unroll
    for (int mf = 0; mf < 2; mf++) {
      float inv = 1.0f / fmaxf(lis[mf], 1e-20f);
      float invr[4];
#pragma unroll
      for (int r = 0; r < 4; r++) invr[r] = __shfl(inv, quad * 4 + r, 16);
#pragma unroll
      for (int ct = 0; ct < 4; ct++)
#pragma unroll
        for (int r = 0; r < 4; r++) {
          int q = wq0 + mf * 16 + quad * 4 + r;
          float v = o_acc[mf][ct][r] * invr[r];
          Oout[(size_t)(b * SEQ + q) * EMBED + h * HDIM + ct * 16 + l15] = f2bf(v);
        }
    }
  }
}

// ---------------------------------------------------------------------------
// ws layout (bytes):
//   flag @ 0          (1024)
//   xb   @ 1024       16777216
//   WTq  @ 16778240    6291456
//   WTo  @ 23069696    2097152
//   bqb  @ 25166848       6144
//   bob  @ 25172992       2048
//   Kw   @ 25175040   16777216
//   Vw   @ 41952256   16777216   (dead after transpose_v -> reused as Aw)
//   VT   @ 58729472   16777216   -> end 75506688
//   Qw   @ 75506688 if ws fits, else Q lives in d_out.
// ---------------------------------------------------------------------------
extern "C" void kernel_launch(void* const* d_in, const int* in_sizes, int n_in,
                              void* d_out, int out_size, void* d_ws, size_t ws_size,
                              hipStream_t stream) {
  const void* x     = d_in[0];
  const void* W_qkv = d_in[2];
  const void* b_qkv = d_in[3];
  const void* W_out = d_in[4];
  const void* b_out = d_in[5];

  char* ws = (char*)d_ws;
  int*    flag = (int*)(ws + 0);
  ushort* xb   = (ushort*)(ws + 1024);
  ushort* WTq  = (ushort*)(ws + 16778240);
  ushort* WTo  = (ushort*)(ws + 23069696);
  ushort* bqb  = (ushort*)(ws + 25166848);
  ushort* bob  = (ushort*)(ws + 25172992);
  ushort* Kw   = (ushort*)(ws + 25175040);
  ushort* Vw   = (ushort*)(ws + 41952256);
  ushort* VTw  = (ushort*)(ws + 58729472);
  ushort* Aw   = Vw;   // Vw dead after transpose_v
  ushort* Qw   = (ws_size >= (size_t)75506688 + 16777216)
                   ? (ushort*)(ws + 75506688)
                   : (ushort*)d_out;   // d_out as scratch: dead until final GEMM

  detect_dtype<<<1, 256, 0, stream>>>((const uint32_t*)x, flag);

  cvt_bf16_v4<<<2048, 256, 0, stream>>>(x, xb, flag, BATCH * SEQ * EMBED / 4);
  cvt_biases<<<16, 256, 0, stream>>>(b_qkv, b_out, bqb, bob, flag);

  transpose_cvt<<<dim3(3072 / 32, 1024 / 32), 256, 0, stream>>>(W_qkv, WTq, flag, 1024, 3072);
  transpose_cvt<<<dim3(1024 / 32, 1024 / 32), 256, 0, stream>>>(W_out, WTo, flag, 1024, 1024);

  gemm128<0><<<dim3(3072 / 128, 8192 / 128), 256, 0, stream>>>(
      xb, WTq, bqb, Qw, Kw, Vw, flag, BATCH * SEQ, 3 * EMBED, EMBED);

  transpose_v<<<dim3(SEQ / 32, HDIM / 32, BATCH * NHEADS), 256, 0, stream>>>(Vw, VTw);

  attn_kernel<<<dim3(SEQ / 256, NHEADS, BATCH), 256, 0, stream>>>(Qw, Kw, VTw, Aw);

  gemm128<1><<<dim3(1024 / 128, 8192 / 128), 256, 0, stream>>>(
      Aw, WTo, bob, (ushort*)d_out, nullptr, nullptr, flag, BATCH * SEQ, EMBED, EMBED);
}

// Round 8
// 380.118 us; speedup vs baseline: 1.5122x; 1.0008x over previous
//
#include <hip/hip_runtime.h>
#include <hip/hip_bf16.h>
#include <cstdint>
#include <cstddef>

#define BATCH  4
#define SEQ    2048
#define EMBED  1024
#define NHEADS 16
#define HDIM   64

typedef __attribute__((ext_vector_type(8))) short  short8;   // 8 x bf16 (4 VGPRs)
typedef __attribute__((ext_vector_type(4))) float  floatx4;  // MFMA C/D

#define MASK_NEG (-1.0e30f)   // finite "minus infinity": no inf-inf NaN paths
#define LOG2E    1.44269504f

__device__ __forceinline__ float bf2f(ushort u) {
  union { uint32_t i; float f; } v; v.i = ((uint32_t)u) << 16; return v.f;
}
__device__ __forceinline__ ushort f2bf(float f) {
  union { float f; uint32_t i; } v; v.f = f;
  uint32_t u = v.i;
  return (ushort)((u + 0x7fffu + ((u >> 16) & 1u)) >> 16);   // RNE
}
// packed RNE f32x2 -> bf16x2 (v_cvt_pk_bf16_f32 on gfx950)
__device__ __forceinline__ uint32_t f2bf_pk(float a, float b) {
  union { __hip_bfloat162 h; uint32_t u; } v;
  v.h = __float22bfloat162_rn(make_float2(a, b));
  return v.u;
}
// async global->LDS 16B/lane; LDS dst must be wave-uniform base + lane*16
__device__ __forceinline__ void gll16(const ushort* g, ushort* l) {
  __builtin_amdgcn_global_load_lds(
      (const __attribute__((address_space(1))) void*)g,
      (__attribute__((address_space(3))) void*)l, 16, 0, 0);
}

// ---------------------------------------------------------------------------
// Dtype detection (flag=1 bf16-packed, 0 fp32). Verified working since round 3.
// ---------------------------------------------------------------------------
__global__ __launch_bounds__(256) void detect_dtype(
    const uint32_t* __restrict__ x, int* __restrict__ flag) {
  __shared__ int sh[256];
  int tid = threadIdx.x;
  int c = 0;
#pragma unroll
  for (int i = 0; i < 16; i++) {
    uint32_t w = x[tid * 16 + i];
    uint32_t lo = w & 0xFFFFu;
    int e = (int)((lo >> 7) & 0xFF);
    if (lo == 0u || (e >= 100 && e <= 140)) c++;
  }
  sh[tid] = c;
  __syncthreads();
  if (tid == 0) {
    int s = 0;
    for (int i = 0; i < 256; i++) s += sh[i];
    *flag = (s >= 3500) ? 1 : 0;
  }
}

// vectorized x conversion: 4 elems/thread/step
__global__ __launch_bounds__(256) void cvt_bf16_v4(
    const void* __restrict__ in, ushort* __restrict__ out,
    const int* __restrict__ flag, int n4) {
  bool isbf = (*flag != 0);
  int stride = gridDim.x * 256;
  for (int i = blockIdx.x * 256 + threadIdx.x; i < n4; i += stride) {
    if (isbf) {
      ((uint2*)out)[i] = ((const uint2*)in)[i];
    } else {
      float4 f = ((const float4*)in)[i];
      uint2 o;
      o.x = f2bf_pk(f.x, f.y);
      o.y = f2bf_pk(f.z, f.w);
      ((uint2*)out)[i] = o;
    }
  }
}

// both biases in one launch: i<3072 -> bqb, else bob
__global__ __launch_bounds__(256) void cvt_biases(
    const void* __restrict__ bq, const void* __restrict__ bo,
    ushort* __restrict__ bqb, ushort* __restrict__ bob,
    const int* __restrict__ flag) {
  bool isbf = (*flag != 0);
  int i = blockIdx.x * 256 + threadIdx.x;
  if (i < 3 * EMBED) {
    bqb[i] = isbf ? ((const ushort*)bq)[i] : f2bf(((const float*)bq)[i]);
  } else {
    int j = i - 3 * EMBED;
    bob[j] = isbf ? ((const ushort*)bo)[j] : f2bf(((const float*)bo)[j]);
  }
}

__global__ __launch_bounds__(256) void transpose_cvt(
    const void* __restrict__ in, ushort* __restrict__ out,
    const int* __restrict__ flag, int R, int C) {
  bool isbf = (*flag != 0);
  __shared__ ushort tile[32][33];
  int bx = blockIdx.x * 32;
  int by = blockIdx.y * 32;
  int tx = threadIdx.x & 31, ty = threadIdx.x >> 5;
#pragma unroll
  for (int i = 0; i < 32; i += 8) {
    size_t idx = (size_t)(by + ty + i) * C + bx + tx;
    tile[ty + i][tx] = isbf ? ((const ushort*)in)[idx] : f2bf(((const float*)in)[idx]);
  }
  __syncthreads();
#pragma unroll
  for (int i = 0; i < 32; i += 8)
    out[(size_t)(bx + ty + i) * R + by + tx] = tile[tx][ty + i];
}

// ---------------------------------------------------------------------------
// Batched transpose: V (BH, S, D) bf16 -> VT (BH, D, S) bf16.
// ---------------------------------------------------------------------------
__global__ __launch_bounds__(256) void transpose_v(
    const ushort* __restrict__ in, ushort* __restrict__ out) {
  __shared__ ushort tile[32][33];
  int bh = blockIdx.z;
  int s0 = blockIdx.x * 32;
  int d0 = blockIdx.y * 32;
  int tx = threadIdx.x & 31, ty = threadIdx.x >> 5;
  const ushort* ip = in + (size_t)bh * SEQ * HDIM;
  ushort* op = out + (size_t)bh * SEQ * HDIM;
#pragma unroll
  for (int i = 0; i < 32; i += 8)
    tile[ty + i][tx] = ip[(size_t)(s0 + ty + i) * HDIM + d0 + tx];
  __syncthreads();
#pragma unroll
  for (int i = 0; i < 32; i += 8)
    op[(size_t)(d0 + ty + i) * SEQ + s0 + tx] = tile[tx][ty + i];
}

// ---------------------------------------------------------------------------
// GEMM (m97-style, unchanged from passing round 6).
// ---------------------------------------------------------------------------
template <int EPI>
__global__ __launch_bounds__(256) void gemm128(
    const ushort* __restrict__ A, const ushort* __restrict__ BT,
    const ushort* __restrict__ bias,
    ushort* __restrict__ out0, ushort* __restrict__ out1, ushort* __restrict__ out2,
    const int* __restrict__ flag,
    int M, int N, int K) {
  __shared__ __align__(16) ushort Al[128 * 32];
  __shared__ __align__(16) ushort Bl[128 * 32];

  const int tid  = threadIdx.x;
  const int lane = tid & 63, wave = tid >> 6;
  const int quad = lane >> 4, l15 = lane & 15;
  const int wm = wave >> 1, wn = wave & 1;
  const int rowA0 = blockIdx.y * 128;
  const int colB0 = blockIdx.x * 128;

  floatx4 acc[4][4] = {};

  const int r0 = tid >> 2, o0 = (tid & 3) * 8;
  const int r1 = r0 + 64;

  for (int kk = 0; kk < K; kk += 32) {
    __syncthreads();
    gll16(&A [(size_t)(rowA0 + r0) * K + kk + o0], &Al[tid * 8]);
    gll16(&A [(size_t)(rowA0 + r1) * K + kk + o0], &Al[(tid + 256) * 8]);
    gll16(&BT[(size_t)(colB0 + r0) * K + kk + o0], &Bl[tid * 8]);
    gll16(&BT[(size_t)(colB0 + r1) * K + kk + o0], &Bl[(tid + 256) * 8]);
    __syncthreads();

    short8 af[4], bf[4];
#pragma unroll
    for (int mt = 0; mt < 4; mt++)
      af[mt] = *(const short8*)&Al[(wm * 64 + mt * 16 + l15) * 32 + quad * 8];
#pragma unroll
    for (int nt = 0; nt < 4; nt++)
      bf[nt] = *(const short8*)&Bl[(wn * 64 + nt * 16 + l15) * 32 + quad * 8];
#pragma unroll
    for (int mt = 0; mt < 4; mt++)
#pragma unroll
      for (int nt = 0; nt < 4; nt++)
        acc[mt][nt] = __builtin_amdgcn_mfma_f32_16x16x32_bf16(af[mt], bf[nt], acc[mt][nt], 0, 0, 0);
  }

  const bool isbf = (EPI == 1) ? (*flag != 0) : true;

#pragma unroll
  for (int mt = 0; mt < 4; mt++)
#pragma unroll
    for (int nt = 0; nt < 4; nt++)
#pragma unroll
      for (int r = 0; r < 4; r++) {
        int row = rowA0 + wm * 64 + mt * 16 + quad * 4 + r;
        int col = colB0 + wn * 64 + nt * 16 + l15;
        float v = acc[mt][nt][r] + bf2f(bias[col]);
        if (EPI == 0) {
          int three = col >> 10, rem = col & 1023, h = rem >> 6, d = rem & 63;
          int b = row >> 11, s = row & 2047;
          ushort* dst = (three == 0) ? out0 : (three == 1) ? out1 : out2;
          dst[((size_t)(b * NHEADS + h) * SEQ + s) * HDIM + d] = f2bf(v);
        } else {
          if (isbf) out0[(size_t)row * N + col] = f2bf(v);
          else      ((float*)out0)[(size_t)row * N + col] = v;
        }
      }
}

// ---------------------------------------------------------------------------
// Flash attention v6: transposed scores (S^T = K·Q^T), lane-owned softmax
// rows; 128-key tiles; single LDS K/V buffer + register prefetch; diagonal
// pairing {i, 15-i}; grid 512 = 2 blocks/CU.
//   v5->v6: mf-OUTER score loop (s[8] for one mf at a time, 32 VGPRs instead
//   of 64) + waves_per_eu(2,2) pin -> full 256-VGPR budget, no scratch spill
//   (round 7 spilled exactly the pk/pv prefetch: 284 MB WRITE_SIZE).
// ---------------------------------------------------------------------------
__global__ __launch_bounds__(256)
__attribute__((amdgpu_waves_per_eu(2, 2)))
void attn_kernel(
    const ushort* __restrict__ Q, const ushort* __restrict__ K,
    const ushort* __restrict__ VT, ushort* __restrict__ Oout) {
  __shared__ __align__(16) ushort Kl[128 * 72];      // [key][d]
  __shared__ __align__(16) ushort Vt[64 * 136];      // [d][key]
  __shared__ __align__(16) ushort Pl[4][32 * 136];   // per-wave [qrow][key]

  const int tid  = threadIdx.x;
  const int lane = tid & 63, wave = tid >> 6;
  const int quad = lane >> 4, l15 = lane & 15;
  const int pair = blockIdx.x;                       // 0..7
  const int h = blockIdx.y, b = blockIdx.z;
  const int bh = b * NHEADS + h;
  const ushort* Qp  = Q  + (size_t)bh * SEQ * HDIM;
  const ushort* Kp  = K  + (size_t)bh * SEQ * HDIM;
  const ushort* VTp = VT + (size_t)bh * SEQ * HDIM;  // [d][s]

  const float slope2 = exp2f(-0.5f * (float)(h + 1)) * LOG2E;
  const float c2 = 0.125f * LOG2E;
  float rt[4];
#pragma unroll
  for (int r = 0; r < 4; r++) rt[r] = slope2 * (float)r;

  const int krow = tid >> 3, koff = (tid & 7) * 8;    // K tile: 128 x 64
  const int vrow = tid >> 4, voff = (tid & 15) * 8;   // V tile: 64 x 128

  for (int qsel = 0; qsel < 2; qsel++) {
    const int qt = qsel ? (15 - pair) : pair;
    const int wq0 = qt * 128 + wave * 32;

    short8 qf[2][2];
#pragma unroll
    for (int mf = 0; mf < 2; mf++) {
      const ushort* qr = &Qp[(size_t)(wq0 + mf * 16 + l15) * HDIM];
      qf[mf][0] = *(const short8*)&qr[quad * 8];
      qf[mf][1] = *(const short8*)&qr[32 + quad * 8];
    }

    float m2s[2] = {MASK_NEG, MASK_NEG}, lis[2] = {0.f, 0.f};
    float qrowf[2];
#pragma unroll
    for (int mf = 0; mf < 2; mf++) qrowf[mf] = (float)(wq0 + mf * 16 + l15);
    floatx4 o_acc[2][4] = {};

    // tile 0 into LDS (barrier first: protect from previous qsel's readers)
    uint4 pk[4], pv[4];
#pragma unroll
    for (int j = 0; j < 4; j++) {
      pk[j] = *(const uint4*)&Kp[(size_t)(krow + 32 * j) * HDIM + koff];
      pv[j] = *(const uint4*)&VTp[(size_t)(vrow + 16 * j) * SEQ + voff];
    }
    __syncthreads();
#pragma unroll
    for (int j = 0; j < 4; j++) {
      *(uint4*)&Kl[(krow + 32 * j) * 72 + koff]  = pk[j];
      *(uint4*)&Vt[(vrow + 16 * j) * 136 + voff] = pv[j];
    }
    __syncthreads();

    for (int kt = 0; kt <= qt; kt++) {
      const int kb = kt * 128;
      const bool more = (kt < qt);
      if (more) {
        const int kb2 = kb + 128;
#pragma unroll
        for (int j = 0; j < 4; j++) {
          pk[j] = *(const uint4*)&Kp[(size_t)(kb2 + krow + 32 * j) * HDIM + koff];
          pv[j] = *(const uint4*)&VTp[(size_t)(vrow + 16 * j) * SEQ + kb2 + voff];
        }
      }

      const bool needs_mask = (kt == qt);   // wave-uniform: only diagonal tile

      // per-mf: scores S^T = K.Q^T (row=key, col=q), then softmax + P-store.
      // mf-outer keeps only s[8] (32 VGPRs) live -> no spill.
#pragma unroll
      for (int mf = 0; mf < 2; mf++) {
        floatx4 sm[8];
#pragma unroll
        for (int kct = 0; kct < 8; kct++) {
          short8 a0 = *(const short8*)&Kl[(kct * 16 + l15) * 72 + quad * 8];
          short8 a1 = *(const short8*)&Kl[(kct * 16 + l15) * 72 + 32 + quad * 8];
          floatx4 z = {};
          z = __builtin_amdgcn_mfma_f32_16x16x32_bf16(a0, qf[mf][0], z, 0, 0, 0);
          sm[kct] = __builtin_amdgcn_mfma_f32_16x16x32_bf16(a1, qf[mf][1], z, 0, 0, 0);
        }

        float mloc = MASK_NEG;
#pragma unroll
        for (int kct = 0; kct < 8; kct++) {
          float keyb = (float)(kb + kct * 16 + quad * 4);
          float base = slope2 * keyb;
#pragma unroll
          for (int r = 0; r < 4; r++) {
            float v = fmaf(sm[kct][r], c2, base + rt[r]);
            if (needs_mask && (keyb + (float)r > qrowf[mf])) v = MASK_NEG;
            sm[kct][r] = v;
            mloc = fmaxf(mloc, v);
          }
        }
        mloc = fmaxf(mloc, __shfl_xor(mloc, 16, 64));
        mloc = fmaxf(mloc, __shfl_xor(mloc, 32, 64));

        float mn = fmaxf(m2s[mf], mloc);
        float al = exp2f(m2s[mf] - mn);
        m2s[mf] = mn;

        float rs = 0.f;
#pragma unroll
        for (int kct = 0; kct < 8; kct++) {
          float p0 = exp2f(sm[kct][0] - mn), p1 = exp2f(sm[kct][1] - mn);
          float p2 = exp2f(sm[kct][2] - mn), p3 = exp2f(sm[kct][3] - mn);
          rs += (p0 + p1) + (p2 + p3);
          uint2 pw;
          pw.x = f2bf_pk(p0, p1);
          pw.y = f2bf_pk(p2, p3);
          *(uint2*)&Pl[wave][(mf * 16 + l15) * 136 + kct * 16 + quad * 4] = pw;
        }
        rs += __shfl_xor(rs, 16, 64);
        rs += __shfl_xor(rs, 32, 64);
        lis[mf] = lis[mf] * al + rs;

        float alr[4];
#pragma unroll
        for (int r = 0; r < 4; r++) alr[r] = __shfl(al, quad * 4 + r, 16);
#pragma unroll
        for (int ct = 0; ct < 4; ct++)
#pragma unroll
          for (int r = 0; r < 4; r++) o_acc[mf][ct][r] *= alr[r];
      }

      // O += P . V  (A = P row-major [q][key] b128, B = Vt; per-wave Pl)
#pragma unroll
      for (int ks = 0; ks < 4; ks++) {
        short8 vf[4];
#pragma unroll
        for (int ct = 0; ct < 4; ct++)
          vf[ct] = *(const short8*)&Vt[(ct * 16 + l15) * 136 + ks * 32 + quad * 8];
#pragma unroll
        for (int mf = 0; mf < 2; mf++) {
          short8 pf = *(const short8*)&Pl[wave][(mf * 16 + l15) * 136 + ks * 32 + quad * 8];
#pragma unroll
          for (int ct = 0; ct < 4; ct++)
            o_acc[mf][ct] = __builtin_amdgcn_mfma_f32_16x16x32_bf16(pf, vf[ct], o_acc[mf][ct], 0, 0, 0);
        }
      }

      if (more) {
        __syncthreads();   // all waves done reading Kl/Vt
#pragma unroll
        for (int j = 0; j < 4; j++) {
          *(uint4*)&Kl[(krow + 32 * j) * 72 + koff]  = pk[j];
          *(uint4*)&Vt[(vrow + 16 * j) * 136 + voff] = pv[j];
        }
        __syncthreads();
      }
    }

    // epilogue: O rows q = wq0+mf*16+quad*4+r, cols d = ct*16+l15
#pragma unroll
    for (int mf = 0; mf < 2; mf++) {
      float inv = 1.0f / fmaxf(lis[mf], 1e-20f);
      float invr[4];
#pragma unroll
      for (int r = 0; r < 4; r++) invr[r] = __shfl(inv, quad * 4 + r, 16);
#pragma unroll
      for (int ct = 0; ct < 4; ct++)
#pragma unroll
        for (int r = 0; r < 4; r++) {
          int q = wq0 + mf * 16 + quad * 4 + r;
          float v = o_acc[mf][ct][r] * invr[r];
          Oout[(size_t)(b * SEQ + q) * EMBED + h * HDIM + ct * 16 + l15] = f2bf(v);
        }
    }
  }
}

// ---------------------------------------------------------------------------
// ws layout (bytes):
//   flag @ 0          (1024)
//   xb   @ 1024       16777216
//   WTq  @ 16778240    6291456
//   WTo  @ 23069696    2097152
//   bqb  @ 25166848       6144
//   bob  @ 25172992       2048
//   Kw   @ 25175040   16777216
//   Vw   @ 41952256   16777216   (dead after transpose_v -> reused as Aw)
//   VT   @ 58729472   16777216   -> end 75506688
//   Qw   @ 75506688 if ws fits, else Q lives in d_out.
// ---------------------------------------------------------------------------
extern "C" void kernel_launch(void* const* d_in, const int* in_sizes, int n_in,
                              void* d_out, int out_size, void* d_ws, size_t ws_size,
                              hipStream_t stream) {
  const void* x     = d_in[0];
  const void* W_qkv = d_in[2];
  const void* b_qkv = d_in[3];
  const void* W_out = d_in[4];
  const void* b_out = d_in[5];

  char* ws = (char*)d_ws;
  int*    flag = (int*)(ws + 0);
  ushort* xb   = (ushort*)(ws + 1024);
  ushort* WTq  = (ushort*)(ws + 16778240);
  ushort* WTo  = (ushort*)(ws + 23069696);
  ushort* bqb  = (ushort*)(ws + 25166848);
  ushort* bob  = (ushort*)(ws + 25172992);
  ushort* Kw   = (ushort*)(ws + 25175040);
  ushort* Vw   = (ushort*)(ws + 41952256);
  ushort* VTw  = (ushort*)(ws + 58729472);
  ushort* Aw   = Vw;   // Vw dead after transpose_v
  ushort* Qw   = (ws_size >= (size_t)75506688 + 16777216)
                   ? (ushort*)(ws + 75506688)
                   : (ushort*)d_out;   // d_out as scratch: dead until final GEMM

  detect_dtype<<<1, 256, 0, stream>>>((const uint32_t*)x, flag);

  cvt_bf16_v4<<<2048, 256, 0, stream>>>(x, xb, flag, BATCH * SEQ * EMBED / 4);
  cvt_biases<<<16, 256, 0, stream>>>(b_qkv, b_out, bqb, bob, flag);

  transpose_cvt<<<dim3(3072 / 32, 1024 / 32), 256, 0, stream>>>(W_qkv, WTq, flag, 1024, 3072);
  transpose_cvt<<<dim3(1024 / 32, 1024 / 32), 256, 0, stream>>>(W_out, WTo, flag, 1024, 1024);

  gemm128<0><<<dim3(3072 / 128, 8192 / 128), 256, 0, stream>>>(
      xb, WTq, bqb, Qw, Kw, Vw, flag, BATCH * SEQ, 3 * EMBED, EMBED);

  transpose_v<<<dim3(SEQ / 32, HDIM / 32, BATCH * NHEADS), 256, 0, stream>>>(Vw, VTw);

  attn_kernel<<<dim3(SEQ / 256, NHEADS, BATCH), 256, 0, stream>>>(Qw, Kw, VTw, Aw);

  gemm128<1><<<dim3(1024 / 128, 8192 / 128), 256, 0, stream>>>(
      Aw, WTo, bob, (ushort*)d_out, nullptr, nullptr, flag, BATCH * SEQ, EMBED, EMBED);
}

// Round 9
// 326.104 us; speedup vs baseline: 1.7627x; 1.1656x over previous
//
#include <hip/hip_runtime.h>
#include <hip/hip_bf16.h>
#include <cstdint>
#include <cstddef>

#define BATCH  4
#define SEQ    2048
#define EMBED  1024
#define NHEADS 16
#define HDIM   64

typedef __attribute__((ext_vector_type(8))) short  short8;   // 8 x bf16 (4 VGPRs)
typedef __attribute__((ext_vector_type(4))) float  floatx4;  // MFMA C/D

#define MASK_NEG (-1.0e30f)   // finite "minus infinity": no inf-inf NaN paths
#define LOG2E    1.44269504f

__device__ __forceinline__ float bf2f(ushort u) {
  union { uint32_t i; float f; } v; v.i = ((uint32_t)u) << 16; return v.f;
}
__device__ __forceinline__ ushort f2bf(float f) {
  union { float f; uint32_t i; } v; v.f = f;
  uint32_t u = v.i;
  return (ushort)((u + 0x7fffu + ((u >> 16) & 1u)) >> 16);   // RNE
}
// packed RNE f32x2 -> bf16x2 (v_cvt_pk_bf16_f32 on gfx950)
__device__ __forceinline__ uint32_t f2bf_pk(float a, float b) {
  union { __hip_bfloat162 h; uint32_t u; } v;
  v.h = __float22bfloat162_rn(make_float2(a, b));
  return v.u;
}
// async global->LDS 16B/lane; LDS dst must be wave-uniform base + lane*16
__device__ __forceinline__ void gll16(const ushort* g, ushort* l) {
  __builtin_amdgcn_global_load_lds(
      (const __attribute__((address_space(1))) void*)g,
      (__attribute__((address_space(3))) void*)l, 16, 0, 0);
}

// ---------------------------------------------------------------------------
// Dtype detection (flag=1 bf16-packed, 0 fp32). Verified working since round 3.
// ---------------------------------------------------------------------------
__global__ __launch_bounds__(256) void detect_dtype(
    const uint32_t* __restrict__ x, int* __restrict__ flag) {
  __shared__ int sh[256];
  int tid = threadIdx.x;
  int c = 0;
#pragma unroll
  for (int i = 0; i < 16; i++) {
    uint32_t w = x[tid * 16 + i];
    uint32_t lo = w & 0xFFFFu;
    int e = (int)((lo >> 7) & 0xFF);
    if (lo == 0u || (e >= 100 && e <= 140)) c++;
  }
  sh[tid] = c;
  __syncthreads();
  if (tid == 0) {
    int s = 0;
    for (int i = 0; i < 256; i++) s += sh[i];
    *flag = (s >= 3500) ? 1 : 0;
  }
}

// vectorized x conversion: 4 elems/thread/step
__global__ __launch_bounds__(256) void cvt_bf16_v4(
    const void* __restrict__ in, ushort* __restrict__ out,
    const int* __restrict__ flag, int n4) {
  bool isbf = (*flag != 0);
  int stride = gridDim.x * 256;
  for (int i = blockIdx.x * 256 + threadIdx.x; i < n4; i += stride) {
    if (isbf) {
      ((uint2*)out)[i] = ((const uint2*)in)[i];
    } else {
      float4 f = ((const float4*)in)[i];
      uint2 o;
      o.x = f2bf_pk(f.x, f.y);
      o.y = f2bf_pk(f.z, f.w);
      ((uint2*)out)[i] = o;
    }
  }
}

// both biases in one launch: i<3072 -> bqb, else bob
__global__ __launch_bounds__(256) void cvt_biases(
    const void* __restrict__ bq, const void* __restrict__ bo,
    ushort* __restrict__ bqb, ushort* __restrict__ bob,
    const int* __restrict__ flag) {
  bool isbf = (*flag != 0);
  int i = blockIdx.x * 256 + threadIdx.x;
  if (i < 3 * EMBED) {
    bqb[i] = isbf ? ((const ushort*)bq)[i] : f2bf(((const float*)bq)[i]);
  } else {
    int j = i - 3 * EMBED;
    bob[j] = isbf ? ((const ushort*)bo)[j] : f2bf(((const float*)bo)[j]);
  }
}

__global__ __launch_bounds__(256) void transpose_cvt(
    const void* __restrict__ in, ushort* __restrict__ out,
    const int* __restrict__ flag, int R, int C) {
  bool isbf = (*flag != 0);
  __shared__ ushort tile[32][33];
  int bx = blockIdx.x * 32;
  int by = blockIdx.y * 32;
  int tx = threadIdx.x & 31, ty = threadIdx.x >> 5;
#pragma unroll
  for (int i = 0; i < 32; i += 8) {
    size_t idx = (size_t)(by + ty + i) * C + bx + tx;
    tile[ty + i][tx] = isbf ? ((const ushort*)in)[idx] : f2bf(((const float*)in)[idx]);
  }
  __syncthreads();
#pragma unroll
  for (int i = 0; i < 32; i += 8)
    out[(size_t)(bx + ty + i) * R + by + tx] = tile[tx][ty + i];
}

// ---------------------------------------------------------------------------
// Batched transpose: V (BH, S, D) bf16 -> VT (BH, D, S) bf16.
// ---------------------------------------------------------------------------
__global__ __launch_bounds__(256) void transpose_v(
    const ushort* __restrict__ in, ushort* __restrict__ out) {
  __shared__ ushort tile[32][33];
  int bh = blockIdx.z;
  int s0 = blockIdx.x * 32;
  int d0 = blockIdx.y * 32;
  int tx = threadIdx.x & 31, ty = threadIdx.x >> 5;
  const ushort* ip = in + (size_t)bh * SEQ * HDIM;
  ushort* op = out + (size_t)bh * SEQ * HDIM;
#pragma unroll
  for (int i = 0; i < 32; i += 8)
    tile[ty + i][tx] = ip[(size_t)(s0 + ty + i) * HDIM + d0 + tx];
  __syncthreads();
#pragma unroll
  for (int i = 0; i < 32; i += 8)
    op[(size_t)(d0 + ty + i) * SEQ + s0 + tx] = tile[tx][ty + i];
}

// ---------------------------------------------------------------------------
// GEMM v2: BK=64 (half the barriers of BK=32), global_load_lds width-16
// staging into XOR-chunk-swizzled unpadded LDS (chunk' = chunk ^ (row&7)):
// b128 frag reads hit all 32 banks (8 lanes per 4-bank span over 8 phases).
// Per-h fragment loading keeps live VGPRs ~110 (no spill at default budget).
// ---------------------------------------------------------------------------
template <int EPI>
__global__ __launch_bounds__(256) void gemm128(
    const ushort* __restrict__ A, const ushort* __restrict__ BT,
    const ushort* __restrict__ bias,
    ushort* __restrict__ out0, ushort* __restrict__ out1, ushort* __restrict__ out2,
    const int* __restrict__ flag,
    int M, int N, int K) {
  __shared__ __align__(16) ushort Al[128 * 64];
  __shared__ __align__(16) ushort Bl[128 * 64];

  const int tid  = threadIdx.x;
  const int lane = tid & 63, wave = tid >> 6;
  const int quad = lane >> 4, l15 = lane & 15;
  const int wm = wave >> 1, wn = wave & 1;
  const int rowA0 = blockIdx.y * 128;
  const int colB0 = blockIdx.x * 128;

  floatx4 acc[4][4] = {};

  // staging: slot s = tid + j*256 (j=0..3) per matrix; row = s>>3, pos = s&7,
  // source chunk c = pos ^ (row&7). LDS elem offset = s*8 (byte = s*16 =
  // wave-uniform base + lane*16, as required by global_load_lds).
  int srow[4], sc8[4];
#pragma unroll
  for (int j = 0; j < 4; j++) {
    int s = tid + j * 256;
    srow[j] = s >> 3;
    sc8[j] = ((s & 7) ^ (srow[j] & 7)) * 8;
  }

  for (int kk = 0; kk < K; kk += 64) {
    __syncthreads();
#pragma unroll
    for (int j = 0; j < 4; j++)
      gll16(&A[(size_t)(rowA0 + srow[j]) * K + kk + sc8[j]], &Al[(tid + j * 256) * 8]);
#pragma unroll
    for (int j = 0; j < 4; j++)
      gll16(&BT[(size_t)(colB0 + srow[j]) * K + kk + sc8[j]], &Bl[(tid + j * 256) * 8]);
    __syncthreads();

#pragma unroll
    for (int h = 0; h < 2; h++) {
      short8 af[4], bf[4];
#pragma unroll
      for (int mt = 0; mt < 4; mt++) {
        int row = wm * 64 + mt * 16 + l15;
        int pos = (quad + 4 * h) ^ (l15 & 7);
        af[mt] = *(const short8*)&Al[row * 64 + pos * 8];
      }
#pragma unroll
      for (int nt = 0; nt < 4; nt++) {
        int row = wn * 64 + nt * 16 + l15;
        int pos = (quad + 4 * h) ^ (l15 & 7);
        bf[nt] = *(const short8*)&Bl[row * 64 + pos * 8];
      }
#pragma unroll
      for (int mt = 0; mt < 4; mt++)
#pragma unroll
        for (int nt = 0; nt < 4; nt++)
          acc[mt][nt] = __builtin_amdgcn_mfma_f32_16x16x32_bf16(af[mt], bf[nt], acc[mt][nt], 0, 0, 0);
    }
  }

  const bool isbf = (EPI == 1) ? (*flag != 0) : true;

#pragma unroll
  for (int mt = 0; mt < 4; mt++)
#pragma unroll
    for (int nt = 0; nt < 4; nt++)
#pragma unroll
      for (int r = 0; r < 4; r++) {
        int row = rowA0 + wm * 64 + mt * 16 + quad * 4 + r;
        int col = colB0 + wn * 64 + nt * 16 + l15;
        float v = acc[mt][nt][r] + bf2f(bias[col]);
        if (EPI == 0) {
          int three = col >> 10, rem = col & 1023, h = rem >> 6, d = rem & 63;
          int b = row >> 11, s = row & 2047;
          ushort* dst = (three == 0) ? out0 : (three == 1) ? out1 : out2;
          dst[((size_t)(b * NHEADS + h) * SEQ + s) * HDIM + d] = f2bf(v);
        } else {
          if (isbf) out0[(size_t)row * N + col] = f2bf(v);
          else      ((float*)out0)[(size_t)row * N + col] = v;
        }
      }
}

// ---------------------------------------------------------------------------
// Flash attention v7: transposed scores (S^T = K·Q^T, lane-owned softmax
// rows) on the round-6 no-spill envelope: 64-key tiles, double-buffered LDS
// with 16-VGPR register prefetch, one barrier/iter, diagonal pairing
// {i, 15-i} (34 iters/block, grid 512 = 2 blocks/CU). Live VGPRs ~110.
// ---------------------------------------------------------------------------
__global__ __launch_bounds__(256, 2) void attn_kernel(
    const ushort* __restrict__ Q, const ushort* __restrict__ K,
    const ushort* __restrict__ VT, ushort* __restrict__ Oout) {
  __shared__ __align__(16) ushort Kl[2][64 * 72];   // [key][d], pad 72
  __shared__ __align__(16) ushort Vt[2][64 * 72];   // [d][key], pad 72
  __shared__ __align__(16) ushort Pl[4][32 * 72];   // per-wave [qrow][key], pad 72 (144B: 16B-aligned rows)

  const int tid  = threadIdx.x;
  const int lane = tid & 63, wave = tid >> 6;
  const int quad = lane >> 4, l15 = lane & 15;
  const int pair = blockIdx.x;                       // 0..7
  const int h = blockIdx.y, b = blockIdx.z;
  const int bh = b * NHEADS + h;
  const ushort* Qp  = Q  + (size_t)bh * SEQ * HDIM;
  const ushort* Kp  = K  + (size_t)bh * SEQ * HDIM;
  const ushort* VTp = VT + (size_t)bh * SEQ * HDIM;  // [d][s]

  const float slope2 = exp2f(-0.5f * (float)(h + 1)) * LOG2E;
  const float c2 = 0.125f * LOG2E;
  float rt[4];
#pragma unroll
  for (int r = 0; r < 4; r++) rt[r] = slope2 * (float)r;

  const int sr0 = tid >> 3,         so0 = (tid & 7) * 8;   // rows 0..31
  const int sr1 = (tid + 256) >> 3, so1 = (tid & 7) * 8;   // rows 32..63

  for (int qsel = 0; qsel < 2; qsel++) {
    const int qt = qsel ? (15 - pair) : pair;
    const int wq0 = qt * 128 + wave * 32;
    const int wqmax = wq0 + 31;

    short8 qf[2][2];
#pragma unroll
    for (int mf = 0; mf < 2; mf++) {
      const ushort* qr = &Qp[(size_t)(wq0 + mf * 16 + l15) * HDIM];
      qf[mf][0] = *(const short8*)&qr[quad * 8];
      qf[mf][1] = *(const short8*)&qr[32 + quad * 8];
    }

    float m2s[2] = {MASK_NEG, MASK_NEG}, lis[2] = {0.f, 0.f};
    float qrowf[2];
#pragma unroll
    for (int mf = 0; mf < 2; mf++) qrowf[mf] = (float)(wq0 + mf * 16 + l15);
    floatx4 o_acc[2][4] = {};

    // tile 0 -> buffer 0 (barrier first: previous qsel's readers)
    uint4 pk0 = *(const uint4*)&Kp[(size_t)sr0 * HDIM + so0];
    uint4 pk1 = *(const uint4*)&Kp[(size_t)sr1 * HDIM + so1];
    uint4 pv0 = *(const uint4*)&VTp[(size_t)sr0 * SEQ + so0];
    uint4 pv1 = *(const uint4*)&VTp[(size_t)sr1 * SEQ + so1];
    __syncthreads();
    *(uint4*)&Kl[0][sr0 * 72 + so0] = pk0;
    *(uint4*)&Kl[0][sr1 * 72 + so1] = pk1;
    *(uint4*)&Vt[0][sr0 * 72 + so0] = pv0;
    *(uint4*)&Vt[0][sr1 * 72 + so1] = pv1;
    __syncthreads();

    const int ntiles = 2 * qt + 2;
    for (int kt = 0; kt < ntiles; kt++) {
      const int kb = kt * 64;
      const int cur = kt & 1;
      const bool more = (kt + 1 < ntiles);

      if (more) {
        const int kb2 = kb + 64;
        pk0 = *(const uint4*)&Kp[(size_t)(kb2 + sr0) * HDIM + so0];
        pk1 = *(const uint4*)&Kp[(size_t)(kb2 + sr1) * HDIM + so1];
        pv0 = *(const uint4*)&VTp[(size_t)sr0 * SEQ + kb2 + so0];
        pv1 = *(const uint4*)&VTp[(size_t)sr1 * SEQ + kb2 + so1];
      }

      if (kb <= wqmax) {
#pragma unroll
        for (int mf = 0; mf < 2; mf++) {
          // S^T = K . Q^T  (row=key, col=q=l15)
          floatx4 sm[4];
#pragma unroll
          for (int kct = 0; kct < 4; kct++) {
            short8 a0 = *(const short8*)&Kl[cur][(kct * 16 + l15) * 72 + quad * 8];
            short8 a1 = *(const short8*)&Kl[cur][(kct * 16 + l15) * 72 + 32 + quad * 8];
            floatx4 z = {};
            z = __builtin_amdgcn_mfma_f32_16x16x32_bf16(a0, qf[mf][0], z, 0, 0, 0);
            sm[kct] = __builtin_amdgcn_mfma_f32_16x16x32_bf16(a1, qf[mf][1], z, 0, 0, 0);
          }

          const bool needs_mask = (kb + 63 > wq0 + mf * 16);
          float mloc = MASK_NEG;
#pragma unroll
          for (int kct = 0; kct < 4; kct++) {
            float keyb = (float)(kb + kct * 16 + quad * 4);
            float base = slope2 * keyb;
#pragma unroll
            for (int r = 0; r < 4; r++) {
              float v = fmaf(sm[kct][r], c2, base + rt[r]);
              if (needs_mask && (keyb + (float)r > qrowf[mf])) v = MASK_NEG;
              sm[kct][r] = v;
              mloc = fmaxf(mloc, v);
            }
          }
          mloc = fmaxf(mloc, __shfl_xor(mloc, 16, 64));
          mloc = fmaxf(mloc, __shfl_xor(mloc, 32, 64));

          float mn = fmaxf(m2s[mf], mloc);
          float al = exp2f(m2s[mf] - mn);
          m2s[mf] = mn;

          float rs = 0.f;
#pragma unroll
          for (int kct = 0; kct < 4; kct++) {
            float p0 = exp2f(sm[kct][0] - mn), p1 = exp2f(sm[kct][1] - mn);
            float p2 = exp2f(sm[kct][2] - mn), p3 = exp2f(sm[kct][3] - mn);
            rs += (p0 + p1) + (p2 + p3);
            uint2 pw;
            pw.x = f2bf_pk(p0, p1);
            pw.y = f2bf_pk(p2, p3);
            *(uint2*)&Pl[wave][(mf * 16 + l15) * 72 + kct * 16 + quad * 4] = pw;
          }
          rs += __shfl_xor(rs, 16, 64);
          rs += __shfl_xor(rs, 32, 64);
          lis[mf] = lis[mf] * al + rs;

          float alr[4];
#pragma unroll
          for (int r = 0; r < 4; r++) alr[r] = __shfl(al, quad * 4 + r, 16);
#pragma unroll
          for (int ct = 0; ct < 4; ct++)
#pragma unroll
            for (int r = 0; r < 4; r++) o_acc[mf][ct][r] *= alr[r];
        }

        // O += P . V  (per-wave Pl; lgkmcnt orders write->read within wave)
#pragma unroll
        for (int ks = 0; ks < 2; ks++) {
          short8 vf[4];
#pragma unroll
          for (int ct = 0; ct < 4; ct++)
            vf[ct] = *(const short8*)&Vt[cur][(ct * 16 + l15) * 72 + ks * 32 + quad * 8];
#pragma unroll
          for (int mf = 0; mf < 2; mf++) {
            short8 pf = *(const short8*)&Pl[wave][(mf * 16 + l15) * 72 + ks * 32 + quad * 8];
#pragma unroll
            for (int ct = 0; ct < 4; ct++)
              o_acc[mf][ct] = __builtin_amdgcn_mfma_f32_16x16x32_bf16(pf, vf[ct], o_acc[mf][ct], 0, 0, 0);
          }
        }
      }

      // drain prefetch into the other buffer (its readers left last iter)
      if (more) {
        const int nxt = cur ^ 1;
        *(uint4*)&Kl[nxt][sr0 * 72 + so0] = pk0;
        *(uint4*)&Kl[nxt][sr1 * 72 + so1] = pk1;
        *(uint4*)&Vt[nxt][sr0 * 72 + so0] = pv0;
        *(uint4*)&Vt[nxt][sr1 * 72 + so1] = pv1;
      }
      __syncthreads();
    }

    // epilogue: O rows q = wq0+mf*16+quad*4+r, cols d = ct*16+l15
#pragma unroll
    for (int mf = 0; mf < 2; mf++) {
      float inv = 1.0f / fmaxf(lis[mf], 1e-20f);
      float invr[4];
#pragma unroll
      for (int r = 0; r < 4; r++) invr[r] = __shfl(inv, quad * 4 + r, 16);
#pragma unroll
      for (int ct = 0; ct < 4; ct++)
#pragma unroll
        for (int r = 0; r < 4; r++) {
          int q = wq0 + mf * 16 + quad * 4 + r;
          float v = o_acc[mf][ct][r] * invr[r];
          Oout[(size_t)(b * SEQ + q) * EMBED + h * HDIM + ct * 16 + l15] = f2bf(v);
        }
    }
  }
}

// ---------------------------------------------------------------------------
// ws layout (bytes):
//   flag @ 0          (1024)
//   xb   @ 1024       16777216
//   WTq  @ 16778240    6291456
//   WTo  @ 23069696    2097152
//   bqb  @ 25166848       6144
//   bob  @ 25172992       2048
//   Kw   @ 25175040   16777216
//   Vw   @ 41952256   16777216   (dead after transpose_v -> reused as Aw)
//   VT   @ 58729472   16777216   -> end 75506688
//   Qw   @ 75506688 if ws fits, else Q lives in d_out.
// ---------------------------------------------------------------------------
extern "C" void kernel_launch(void* const* d_in, const int* in_sizes, int n_in,
                              void* d_out, int out_size, void* d_ws, size_t ws_size,
                              hipStream_t stream) {
  const void* x     = d_in[0];
  const void* W_qkv = d_in[2];
  const void* b_qkv = d_in[3];
  const void* W_out = d_in[4];
  const void* b_out = d_in[5];

  char* ws = (char*)d_ws;
  int*    flag = (int*)(ws + 0);
  ushort* xb   = (ushort*)(ws + 1024);
  ushort* WTq  = (ushort*)(ws + 16778240);
  ushort* WTo  = (ushort*)(ws + 23069696);
  ushort* bqb  = (ushort*)(ws + 25166848);
  ushort* bob  = (ushort*)(ws + 25172992);
  ushort* Kw   = (ushort*)(ws + 25175040);
  ushort* Vw   = (ushort*)(ws + 41952256);
  ushort* VTw  = (ushort*)(ws + 58729472);
  ushort* Aw   = Vw;   // Vw dead after transpose_v
  ushort* Qw   = (ws_size >= (size_t)75506688 + 16777216)
                   ? (ushort*)(ws + 75506688)
                   : (ushort*)d_out;   // d_out as scratch: dead until final GEMM

  detect_dtype<<<1, 256, 0, stream>>>((const uint32_t*)x, flag);

  cvt_bf16_v4<<<2048, 256, 0, stream>>>(x, xb, flag, BATCH * SEQ * EMBED / 4);
  cvt_biases<<<16, 256, 0, stream>>>(b_qkv, b_out, bqb, bob, flag);

  transpose_cvt<<<dim3(3072 / 32, 1024 / 32), 256, 0, stream>>>(W_qkv, WTq, flag, 1024, 3072);
  transpose_cvt<<<dim3(1024 / 32, 1024 / 32), 256, 0, stream>>>(W_out, WTo, flag, 1024, 1024);

  gemm128<0><<<dim3(3072 / 128, 8192 / 128), 256, 0, stream>>>(
      xb, WTq, bqb, Qw, Kw, Vw, flag, BATCH * SEQ, 3 * EMBED, EMBED);

  transpose_v<<<dim3(SEQ / 32, HDIM / 32, BATCH * NHEADS), 256, 0, stream>>>(Vw, VTw);

  attn_kernel<<<dim3(SEQ / 256, NHEADS, BATCH), 256, 0, stream>>>(Qw, Kw, VTw, Aw);

  gemm128<1><<<dim3(1024 / 128, 8192 / 128), 256, 0, stream>>>(
      Aw, WTo, bob, (ushort*)d_out, nullptr, nullptr, flag, BATCH * SEQ, EMBED, EMBED);
}